// Round 5
// baseline (684.449 us; speedup 1.0000x reference)
//
#include <hip/hip_runtime.h>

#define NN 50000
#define EE 800000
#define MM 3
#define HH 2
#define IND 128
#define HIDD 64
#define HEADD 32
#define OUTD 16
#define ATTD 128

#define NPART 8
#define PSZ 6250

#define NB4 12500          // NN/4 int4 groups per metapath
#define SB 49              // scan blocks per metapath

#define NG4 200000         // EE/4 int4 groups per metapath
#define BBLK 196           // bucket blocks per metapath (196*1024 >= 200000)
#define QCAP 105000        // queue capacity per (m,part); E[len]=100k, sigma~296
#define QSUB 16            // sub-blocks per (m,part) in qdeg/qfill

typedef unsigned short u16;
typedef short bf16x8 __attribute__((ext_vector_type(8)));
typedef float f32x4 __attribute__((ext_vector_type(4)));

__device__ __forceinline__ float lrelu(float v) { return v > 0.f ? v : 0.1f * v; }

__device__ __forceinline__ float fast_tanh(float x) {
    float ax = fabsf(x);
    float e = __expf(-2.0f * ax);
    float t = (1.0f - e) * __builtin_amdgcn_rcpf(1.0f + e);
    return copysignf(t, x);
}

__device__ __forceinline__ u16 f2b(float f) {          // fp32 -> bf16 RNE
    union { float f; unsigned int u; } v; v.f = f;
    unsigned int r = v.u + 0x7fffu + ((v.u >> 16) & 1u);
    return (u16)(r >> 16);
}
__device__ __forceinline__ float b2f(u16 u) {
    union { unsigned int u; float f; } v; v.u = ((unsigned int)u) << 16; return v.f;
}

// ================= phase A: bucket edges by dst-part (single read of ei) =================
__global__ __launch_bounds__(256) void k_bucket(const int* __restrict__ ei,
                                                int2* __restrict__ queues,
                                                int* __restrict__ gcur) {
    __shared__ int cnt[NPART];
    __shared__ int base[NPART];
    const int m = blockIdx.y, tid = threadIdx.x;
    const int4* s4 = (const int4*)(ei + (size_t)m * 2 * EE);
    const int4* d4 = (const int4*)(ei + (size_t)m * 2 * EE + EE);
    const int q0 = blockIdx.x * 1024;
    if (tid < NPART) cnt[tid] = 0;
    __syncthreads();
    // pass 1: count
#pragma unroll
    for (int i = 0; i < 4; i++) {
        int q = q0 + i * 256 + tid;
        if (q < NG4) {
            int4 dv = d4[q];
            atomicAdd(&cnt[dv.x / PSZ], 1);
            atomicAdd(&cnt[dv.y / PSZ], 1);
            atomicAdd(&cnt[dv.z / PSZ], 1);
            atomicAdd(&cnt[dv.w / PSZ], 1);
        }
    }
    __syncthreads();
    if (tid < NPART) { base[tid] = atomicAdd(&gcur[m * NPART + tid], cnt[tid]); cnt[tid] = 0; }
    __syncthreads();
    // pass 2: append (src,dst) pairs (chunk re-read is L2-warm)
#pragma unroll
    for (int i = 0; i < 4; i++) {
        int q = q0 + i * 256 + tid;
        if (q < NG4) {
            int4 dv = d4[q];
            int4 sv = s4[q];
            int ds[4] = {dv.x, dv.y, dv.z, dv.w};
            int ss[4] = {sv.x, sv.y, sv.z, sv.w};
#pragma unroll
            for (int e = 0; e < 4; e++) {
                int p = ds[e] / PSZ;
                int slot = base[p] + atomicAdd(&cnt[p], 1);
                if (slot < QCAP)
                    queues[((size_t)(m * NPART + p)) * QCAP + slot] = make_int2(ss[e], ds[e]);
            }
        }
    }
}

// ================= phase B: degree count from own queue (XCD-pinned part) =================
__global__ __launch_bounds__(256) void k_qdeg(const int2* __restrict__ queues,
                                              const int* __restrict__ gcur,
                                              int* __restrict__ deg) {
    const int m = blockIdx.y;
    const int p = blockIdx.x & 7, sub = blockIdx.x >> 3;
    int qlen = gcur[m * NPART + p];
    if (qlen > QCAP) qlen = QCAP;
    const int per = (qlen + QSUB - 1) / QSUB;
    const int beg = sub * per;
    const int end = min(beg + per, qlen);
    const int2* q = queues + ((size_t)(m * NPART + p)) * QCAP;
    int* dg = deg + m * NN;
    for (int i = beg + threadIdx.x; i < end; i += 256)
        atomicAdd(&dg[q[i].y], 1);
}

// ---- scan phase 1: per-block sums of 1024 degrees ----
__global__ __launch_bounds__(256) void k_scan1(const int* __restrict__ deg, int* __restrict__ bsum) {
    __shared__ int wsum[4];
    const int m = blockIdx.y, b = blockIdx.x, tid = threadIdx.x;
    const int4* d4 = (const int4*)(deg + (size_t)m * NN);
    int idx4 = b * 256 + tid;
    int s = 0;
    if (idx4 < NB4) { int4 v = d4[idx4]; s = v.x + v.y + v.z + v.w; }
    const int lane = tid & 63, w = tid >> 6;
    int v = s;
    for (int off = 1; off < 64; off <<= 1) { int t = __shfl_up(v, off); if (lane >= off) v += t; }
    if (lane == 63) wsum[w] = v;
    __syncthreads();
    if (tid == 0) bsum[m * SB + b] = wsum[0] + wsum[1] + wsum[2] + wsum[3];
}

// ---- scan phase 2: exclusive scan of the 3x49 block sums (in place) ----
__global__ __launch_bounds__(256) void k_scan2(int* __restrict__ bsum) {
    __shared__ int ld[MM * SB];
    const int tid = threadIdx.x;
    if (tid < MM * SB) ld[tid] = bsum[tid];
    __syncthreads();
    if (tid < MM) {
        int run = 0;
        for (int b = 0; b < SB; b++) { int t = ld[tid * SB + b]; ld[tid * SB + b] = run; run += t; }
    }
    __syncthreads();
    if (tid < MM * SB) bsum[tid] = ld[tid];
}

// ---- scan phase 3: intra-block scan + write ofs (exclusive) + rs ----
__global__ __launch_bounds__(256) void k_scan3(const int* __restrict__ deg, const int* __restrict__ bsum,
                                               int* __restrict__ ofs, float* __restrict__ rs) {
    __shared__ int wsum[4];
    const int m = blockIdx.y, b = blockIdx.x, tid = threadIdx.x;
    const int4* d4 = (const int4*)(deg + (size_t)m * NN);
    int* o = ofs + (size_t)m * (NN + 1);
    float* r = rs + (size_t)m * NN;
    int idx4 = b * 256 + tid;
    int4 dv = make_int4(0, 0, 0, 0);
    if (idx4 < NB4) dv = d4[idx4];
    int s = dv.x + dv.y + dv.z + dv.w;
    const int lane = tid & 63, w = tid >> 6;
    int v = s;
    for (int off = 1; off < 64; off <<= 1) { int t = __shfl_up(v, off); if (lane >= off) v += t; }
    if (lane == 63) wsum[w] = v;
    __syncthreads();
    int wexcl = 0;
    for (int j = 0; j < 4; j++) if (j < w) wexcl += wsum[j];
    int base = bsum[m * SB + b] + wexcl + (v - s);
    if (idx4 < NB4) {
        int e0 = base, e1 = e0 + dv.x, e2 = e1 + dv.y, e3 = e2 + dv.z;
        ((int4*)o)[idx4] = make_int4(e0, e1, e2, e3);
        float4 rv;
        rv.x = rsqrtf((float)(dv.x + 1));
        rv.y = rsqrtf((float)(dv.y + 1));
        rv.z = rsqrtf((float)(dv.z + 1));
        rv.w = rsqrtf((float)(dv.w + 1));
        ((float4*)r)[idx4] = rv;
    }
    if (b == SB - 1 && tid == 0) o[NN] = EE;
}

// ================= phase C: CSR fill from own queue (XCD-pinned part) =================
__global__ __launch_bounds__(256) void k_qfill(const int2* __restrict__ queues,
                                               const int* __restrict__ gcur,
                                               const int* __restrict__ ofs,
                                               int* __restrict__ cur,
                                               int* __restrict__ sorted) {
    const int m = blockIdx.y;
    const int p = blockIdx.x & 7, sub = blockIdx.x >> 3;
    int qlen = gcur[m * NPART + p];
    if (qlen > QCAP) qlen = QCAP;
    const int per = (qlen + QSUB - 1) / QSUB;
    const int beg = sub * per;
    const int end = min(beg + per, qlen);
    const int2* q = queues + ((size_t)(m * NPART + p)) * QCAP;
    const int* of = ofs + (size_t)m * (NN + 1);
    int* cu = cur + (size_t)m * NN;
    int* srt = sorted + (size_t)m * EE;
    for (int i = beg + threadIdx.x; i < end; i += 256) {
        int2 e = q[i];
        int pos = of[e.y] + atomicAdd(&cu[e.y], 1);
        srt[pos] = e.x;
    }
}

// ================= weight prep: fp32 -> bf16 MFMA B-fragment layout =================
__global__ __launch_bounds__(256) void k_prep(const float* __restrict__ We, const float* __restrict__ Wc,
                                              const float* __restrict__ Wd, const float* __restrict__ Ws,
                                              u16* __restrict__ wbe, u16* __restrict__ wbc,
                                              u16* __restrict__ wbd, u16* __restrict__ wbs) {
    int t = blockIdx.x * 256 + threadIdx.x;
    if (t >= 11776) return;
    bf16x8 val;
    u16* dst;
    if (t < 6144) {                       // enc: per m, 8 nt x 4 ks x 64 lanes, K=128, N=128
        int m = t >> 11, r = t & 2047;
        int nt = r >> 8, ks = (r >> 6) & 3, lane = r & 63;
        int n = nt * 16 + (lane & 15), h = n >> 6, o = n & 63;
        int kb = ks * 32 + (lane >> 4) * 8;
        const float* w = We + ((size_t)(m * 2 + h) * 128) * 64;
#pragma unroll
        for (int j = 0; j < 8; j++) val[j] = (short)f2b(w[(size_t)(kb + j) * 64 + o]);
        dst = wbe + ((size_t)m * 2048 + r) * 8;
    } else if (t < 9216) {                // conv: per m, 8 nt x 2 ks, K=64, N=128 (head-blockdiag)
        int u = t - 6144;
        int m = u >> 10, r = u & 1023;
        int nt = r >> 7, ks = (r >> 6) & 1, lane = r & 63;
        int h = nt >> 2, o = (nt & 3) * 16 + (lane & 15);
        int kb = ks * 32 + (lane >> 4) * 8;
        const float* w = Wc + ((size_t)(m * 2 + h) * 64) * 64;
#pragma unroll
        for (int j = 0; j < 8; j++) val[j] = (short)f2b(w[(size_t)(kb + j) * 64 + o]);
        dst = wbc + ((size_t)m * 1024 + r) * 8;
    } else if (t < 10752) {               // dec: per m, 4 nt x 2 ks, K=64, N=64 (head-blockdiag)
        int u = t - 9216;
        int m = u >> 9, r = u & 511;
        int nt = r >> 7, ks = (r >> 6) & 1, lane = r & 63;
        int h = nt >> 1, o = (nt & 1) * 16 + (lane & 15);
        int kb = ks * 32 + (lane >> 4) * 8;
        const float* w = Wd + ((size_t)(m * 2 + h) * 64) * 32;
#pragma unroll
        for (int j = 0; j < 8; j++) val[j] = (short)f2b(w[(size_t)(kb + j) * 32 + o]);
        dst = wbd + ((size_t)m * 512 + r) * 8;
    } else {                              // W_s: 8 nt x 2 ks, K=64, N=128
        int r = t - 10752;
        int nt = r >> 7, ks = (r >> 6) & 1, lane = r & 63;
        int n = nt * 16 + (lane & 15);
        int kb = ks * 32 + (lane >> 4) * 8;
#pragma unroll
        for (int j = 0; j < 8; j++) val[j] = (short)f2b(Ws[(size_t)(kb + j) * 128 + n]);
        dst = wbs + (size_t)r * 8;
    }
    *(bf16x8*)dst = val;
}

// ================= fused enc+conv: xw = (lrelu(x@We+be)) @ Wc, h tile via LDS =================
#define HLS 133   // fp32 row stride: 5*r mod 32 -> 2 lanes/bank (free)
__global__ __launch_bounds__(256) void k_encconv(const float* __restrict__ x,
                                                 const u16* __restrict__ wbe,
                                                 const float* __restrict__ be,
                                                 const u16* __restrict__ wbc,
                                                 u16* __restrict__ xw) {
    __shared__ float hl[64 * HLS];
    const int tid = threadIdx.x, lane = tid & 63, wave = tid >> 6;
    const int quad = lane >> 4, c16 = lane & 15;
    const int row = blockIdx.x * 64 + wave * 16 + c16;
    const bool ok = row < NN;
    const bf16x8* wbE = (const bf16x8*)wbe;
    f32x4 zero = {0.f, 0.f, 0.f, 0.f};
    f32x4 acc[8];
#pragma unroll
    for (int nt = 0; nt < 8; nt++) acc[nt] = zero;
#pragma unroll
    for (int ks = 0; ks < 4; ks++) {
        bf16x8 a = {0, 0, 0, 0, 0, 0, 0, 0};
        if (ok) {
            const float* xp = x + (size_t)row * 128 + ks * 32 + quad * 8;
            float4 xa = *(const float4*)xp;
            float4 xb = *(const float4*)(xp + 4);
            a[0] = (short)f2b(xa.x); a[1] = (short)f2b(xa.y);
            a[2] = (short)f2b(xa.z); a[3] = (short)f2b(xa.w);
            a[4] = (short)f2b(xb.x); a[5] = (short)f2b(xb.y);
            a[6] = (short)f2b(xb.z); a[7] = (short)f2b(xb.w);
        }
#pragma unroll
        for (int nt = 0; nt < 8; nt++)
            acc[nt] = __builtin_amdgcn_mfma_f32_16x16x32_bf16(a, wbE[(nt * 4 + ks) * 64 + lane], acc[nt], 0, 0, 0);
    }
    const int rbl = wave * 16 + quad * 4;
#pragma unroll
    for (int nt = 0; nt < 8; nt++) {
        int col = nt * 16 + c16, hh = col >> 6, o = col & 63;
        float bias = be[hh * 64 + o];
#pragma unroll
        for (int j = 0; j < 4; j++) {
            int rl = rbl + j;
            int rg = blockIdx.x * 64 + rl;
            hl[rl * HLS + col] = (rg < NN) ? lrelu(acc[nt][j] + bias) : 0.f;
        }
    }
    __syncthreads();
    const bf16x8* wbC = (const bf16x8*)wbc;
    f32x4 cacc[8];
#pragma unroll
    for (int nt = 0; nt < 8; nt++) cacc[nt] = zero;
    const int rl = wave * 16 + c16;
#pragma unroll
    for (int ks = 0; ks < 2; ks++) {
        bf16x8 a0, a1;
        const float* hp = &hl[rl * HLS + ks * 32 + quad * 8];
#pragma unroll
        for (int j = 0; j < 8; j++) { a0[j] = (short)f2b(hp[j]); a1[j] = (short)f2b(hp[64 + j]); }
#pragma unroll
        for (int nt = 0; nt < 8; nt++)
            cacc[nt] = __builtin_amdgcn_mfma_f32_16x16x32_bf16(nt < 4 ? a0 : a1, wbC[(nt * 2 + ks) * 64 + lane], cacc[nt], 0, 0, 0);
    }
#pragma unroll
    for (int nt = 0; nt < 8; nt++) {
        int col = nt * 16 + c16;
#pragma unroll
        for (int j = 0; j < 4; j++) {
            int r = blockIdx.x * 64 + rbl + j;
            if (r < NN) xw[(size_t)r * 128 + col] = f2b(cacc[nt][j]);
        }
    }
}

// ================= gather: gg[dst] = rs[dst] * sum_src rs[src]*xw[src] =================
__global__ __launch_bounds__(256) void k_gather(const int* __restrict__ sorted,
                                                const int* __restrict__ ofs,
                                                const float* __restrict__ rs,
                                                const u16* __restrict__ xw,
                                                u16* __restrict__ gg) {
    const int tid = threadIdx.x;
    const int dst = blockIdx.x * 4 + (tid >> 6);
    if (dst >= NN) return;
    const int lane = tid & 63, p = lane >> 5, c = lane & 31;
    int beg = ofs[dst], end = ofs[dst + 1];
    float a0 = 0.f, a1 = 0.f, a2 = 0.f, a3 = 0.f;
    for (int j = beg + p; j < end; j += 2) {
        int s = sorted[j];
        float cf = rs[s];
        ushort4 v = *(const ushort4*)&xw[(size_t)s * 128 + c * 4];
        a0 = fmaf(cf, b2f(v.x), a0);
        a1 = fmaf(cf, b2f(v.y), a1);
        a2 = fmaf(cf, b2f(v.z), a2);
        a3 = fmaf(cf, b2f(v.w), a3);
    }
    a0 += __shfl_down(a0, 32);
    a1 += __shfl_down(a1, 32);
    a2 += __shfl_down(a2, 32);
    a3 += __shfl_down(a3, 32);
    if (p == 0) {
        float rsd = rs[dst];
        ushort4 o;
        o.x = f2b(a0 * rsd); o.y = f2b(a1 * rsd);
        o.z = f2b(a2 * rsd); o.w = f2b(a3 * rsd);
        *(ushort4*)&gg[(size_t)dst * 128 + c * 4] = o;
    }
}

// ================= post+score =================
__global__ __launch_bounds__(256) void k_post(const u16* __restrict__ gg,
                                              const u16* __restrict__ xw,
                                              const float* __restrict__ rs,
                                              const float* __restrict__ bconv,
                                              const u16* __restrict__ wbd,
                                              const float* __restrict__ bdec,
                                              const u16* __restrict__ wbs,
                                              const float* __restrict__ bs,
                                              const float* __restrict__ qv,
                                              float* __restrict__ z,
                                              float* __restrict__ score, int m) {
    __shared__ float zl[64 * 68];
    const int tid = threadIdx.x, lane = tid & 63, wave = tid >> 6;
    const int quad = lane >> 4, c16 = lane & 15;
    const int row = blockIdx.x * 64 + wave * 16 + c16;
    const bool ok = row < NN;
    float rs2 = 0.f;
    if (ok) { float t = rs[row]; rs2 = t * t; }
    const bf16x8* wd = (const bf16x8*)wbd;
    f32x4 acc[4];
    f32x4 zero = {0.f, 0.f, 0.f, 0.f};
#pragma unroll
    for (int nt = 0; nt < 4; nt++) acc[nt] = zero;
#pragma unroll
    for (int ks = 0; ks < 2; ks++) {
        bf16x8 a0 = {0,0,0,0,0,0,0,0}, a1 = {0,0,0,0,0,0,0,0};
        if (ok) {
            int k0 = ks * 32 + quad * 8;
            const u16* gp0 = &gg[(size_t)row * 128 + k0];
            const u16* xp0 = &xw[(size_t)row * 128 + k0];
            const u16* gp1 = gp0 + 64;
            const u16* xp1 = xp0 + 64;
#pragma unroll
            for (int j = 0; j < 8; j++) {
                float v0 = lrelu(fmaf(b2f(xp0[j]), rs2, b2f(gp0[j])) + bconv[k0 + j]);
                float v1 = lrelu(fmaf(b2f(xp1[j]), rs2, b2f(gp1[j])) + bconv[64 + k0 + j]);
                a0[j] = (short)f2b(v0);
                a1[j] = (short)f2b(v1);
            }
        }
#pragma unroll
        for (int nt = 0; nt < 4; nt++)
            acc[nt] = __builtin_amdgcn_mfma_f32_16x16x32_bf16(nt < 2 ? a0 : a1, wd[(nt * 2 + ks) * 64 + lane], acc[nt], 0, 0, 0);
    }
    const int rbl = wave * 16 + quad * 4;
#pragma unroll
    for (int nt = 0; nt < 4; nt++) {
        int col = nt * 16 + c16, hh = col >> 5, o = col & 31;
        float bias = bdec[hh * 32 + o];
#pragma unroll
        for (int j = 0; j < 4; j++) {
            int rl = rbl + j;
            int rg = blockIdx.x * 64 + rl;
            zl[rl * 68 + col] = (rg < NN) ? (acc[nt][j] + bias) : 0.f;
        }
    }
    __syncthreads();
    {
        int rl = tid >> 2, cq = tid & 3;
        int rg = blockIdx.x * 64 + rl;
        if (rg < NN) {
#pragma unroll
            for (int i = 0; i < 4; i++) {
                int c4 = (cq * 4 + i) * 4;
                *(float4*)&z[(size_t)rg * 64 + c4] = *(const float4*)&zl[rl * 68 + c4];
            }
        }
    }
    const bf16x8* wsb = (const bf16x8*)wbs;
    f32x4 sa[8];
#pragma unroll
    for (int nt = 0; nt < 8; nt++) sa[nt] = zero;
#pragma unroll
    for (int ks = 0; ks < 2; ks++) {
        bf16x8 a;
        const float* zp = &zl[(wave * 16 + c16) * 68 + ks * 32 + quad * 8];
#pragma unroll
        for (int j = 0; j < 8; j++) a[j] = (short)f2b(zp[j]);
#pragma unroll
        for (int nt = 0; nt < 8; nt++)
            sa[nt] = __builtin_amdgcn_mfma_f32_16x16x32_bf16(a, wsb[(nt * 2 + ks) * 64 + lane], sa[nt], 0, 0, 0);
    }
    float s = 0.f;
#pragma unroll
    for (int nt = 0; nt < 8; nt++) {
        int col = nt * 16 + c16;
        float qc = qv[col], bb = bs[col];
#pragma unroll
        for (int j = 0; j < 4; j++) {
            int rg = blockIdx.x * 64 + rbl + j;
            if (rg < NN) s += fast_tanh(sa[nt][j] + bb) * qc;
        }
    }
#pragma unroll
    for (int off = 1; off < 64; off <<= 1) s += __shfl_xor(s, off);
    if (lane == 0) atomicAdd(&score[m], s);
}

// ================= beta =================
__global__ void k_beta(const float* __restrict__ score, float* __restrict__ beta_ws,
                       float* __restrict__ out) {
    if (threadIdx.x == 0) {
        float s0 = score[0] / (float)NN, s1 = score[1] / (float)NN, s2 = score[2] / (float)NN;
        float mx = fmaxf(s0, fmaxf(s1, s2));
        float e0 = expf(s0 - mx), e1 = expf(s1 - mx), e2 = expf(s2 - mx);
        float inv = 1.f / (e0 + e1 + e2);
        beta_ws[0] = e0 * inv; beta_ws[1] = e1 * inv; beta_ws[2] = e2 * inv;
        out[800000] = e0 * inv; out[800001] = e1 * inv; out[800002] = e2 * inv;
    }
}

// ================= output =================
__global__ __launch_bounds__(256) void k_out(const float* __restrict__ z,
                                             const float* __restrict__ beta,
                                             const float* __restrict__ Wo,
                                             const float* __restrict__ bo,
                                             float* __restrict__ out) {
    __shared__ float Zt[64 * 68];
    __shared__ float Wl[64 * 16];
    __shared__ float bl[16];
    const int tid = threadIdx.x, nbase = blockIdx.x * 64;
    float b0 = beta[0], b1 = beta[1], b2 = beta[2];
    for (int qq = tid; qq < 64 * 16; qq += 256) {
        int node = qq >> 4, k4 = qq & 15;
        int ng = nbase + node;
        float4 v = make_float4(0.f, 0.f, 0.f, 0.f);
        if (ng < NN) {
            float4 z0 = *(const float4*)&z[((size_t)0 * NN + ng) * 64 + k4 * 4];
            float4 z1 = *(const float4*)&z[((size_t)1 * NN + ng) * 64 + k4 * 4];
            float4 z2 = *(const float4*)&z[((size_t)2 * NN + ng) * 64 + k4 * 4];
            v.x = b0 * z0.x + b1 * z1.x + b2 * z2.x;
            v.y = b0 * z0.y + b1 * z1.y + b2 * z2.y;
            v.z = b0 * z0.z + b1 * z1.z + b2 * z2.z;
            v.w = b0 * z0.w + b1 * z1.w + b2 * z2.w;
        }
        *(float4*)&Zt[node * 68 + k4 * 4] = v;
    }
    for (int qq = tid; qq < 64 * 16 / 4; qq += 256)
        ((float4*)Wl)[qq] = ((const float4*)Wo)[qq];
    if (tid < 16) bl[tid] = bo[tid];
    __syncthreads();

    const int node = tid >> 2, cg = tid & 3;
    float4 a = make_float4(bl[cg * 4 + 0], bl[cg * 4 + 1], bl[cg * 4 + 2], bl[cg * 4 + 3]);
    for (int k = 0; k < 64; k++) {
        float zv = Zt[node * 68 + k];
        float4 w = *(const float4*)&Wl[k * 16 + cg * 4];
        a.x = fmaf(zv, w.x, a.x);
        a.y = fmaf(zv, w.y, a.y);
        a.z = fmaf(zv, w.z, a.z);
        a.w = fmaf(zv, w.w, a.w);
    }
    float mx = fmaxf(fmaxf(a.x, a.y), fmaxf(a.z, a.w));
    mx = fmaxf(mx, __shfl_xor(mx, 1));
    mx = fmaxf(mx, __shfl_xor(mx, 2));
    float sm = expf(a.x - mx) + expf(a.y - mx) + expf(a.z - mx) + expf(a.w - mx);
    sm += __shfl_xor(sm, 1);
    sm += __shfl_xor(sm, 2);
    float lse = mx + logf(sm);
    int ng = nbase + node;
    if (ng < NN) {
        float4 r = make_float4(a.x - lse, a.y - lse, a.z - lse, a.w - lse);
        *(float4*)&out[(size_t)ng * 16 + cg * 4] = r;
    }
}

extern "C" void kernel_launch(void* const* d_in, const int* in_sizes, int n_in,
                              void* d_out, int out_size, void* d_ws, size_t ws_size,
                              hipStream_t stream) {
    const float* x      = (const float*)d_in[0];
    const int*   ei     = (const int*)d_in[1];
    const float* W_enc  = (const float*)d_in[2];
    const float* b_enc  = (const float*)d_in[3];
    const float* W_conv = (const float*)d_in[4];
    const float* b_conv = (const float*)d_in[5];
    const float* W_dec  = (const float*)d_in[6];
    const float* b_dec  = (const float*)d_in[7];
    const float* W_s    = (const float*)d_in[8];
    const float* b_s    = (const float*)d_in[9];
    const float* qv     = (const float*)d_in[10];
    const float* W_o    = (const float*)d_in[11];
    const float* b_o    = (const float*)d_in[12];
    float* out = (float*)d_out;

    char* ws = (char*)d_ws;
    size_t off = 0;
    auto alloc = [&](size_t bytes) -> char* {
        char* p = ws + off;
        off = (off + bytes + 255) & ~(size_t)255;
        return p;
    };
    int*   deg_i   = (int*)alloc((size_t)MM * NN * 4);
    int*   row_ofs = (int*)alloc((size_t)MM * (NN + 1) * 4);
    int*   cur_i   = (int*)alloc((size_t)MM * NN * 4);
    float* rs      = (float*)alloc((size_t)MM * NN * 4);
    int*   sorted  = (int*)alloc((size_t)MM * EE * 4);
    int2*  queues  = (int2*)alloc((size_t)MM * NPART * QCAP * 8);
    int*   gcur    = (int*)alloc((size_t)MM * NPART * 4);
    int*   bsum    = (int*)alloc((size_t)MM * SB * 4);
    float* score   = (float*)alloc(64);
    float* beta_ws = (float*)alloc(64);
    u16*   wbe     = (u16*)alloc((size_t)MM * 2048 * 8 * 2);
    u16*   wbc     = (u16*)alloc((size_t)MM * 1024 * 8 * 2);
    u16*   wbd     = (u16*)alloc((size_t)MM * 512 * 8 * 2);
    u16*   wbs     = (u16*)alloc((size_t)1024 * 8 * 2);
    u16*   xw_buf  = (u16*)alloc((size_t)NN * 128 * 2);
    u16*   gg_buf  = (u16*)alloc((size_t)NN * 128 * 2);
    float* z_buf   = (float*)alloc((size_t)MM * NN * 64 * 4);

    hipMemsetAsync(deg_i, 0, (size_t)MM * NN * 4, stream);
    hipMemsetAsync(cur_i, 0, (size_t)MM * NN * 4, stream);
    hipMemsetAsync(gcur, 0, (size_t)MM * NPART * 4, stream);
    hipMemsetAsync(score, 0, 16, stream);

    dim3 gbkt(BBLK, MM);
    dim3 gq(NPART * QSUB, MM);
    dim3 gscan(SB, MM);
    k_bucket<<<gbkt, 256, 0, stream>>>(ei, queues, gcur);
    k_qdeg<<<gq, 256, 0, stream>>>(queues, gcur, deg_i);
    k_scan1<<<gscan, 256, 0, stream>>>(deg_i, bsum);
    k_scan2<<<1, 256, 0, stream>>>(bsum);
    k_scan3<<<gscan, 256, 0, stream>>>(deg_i, bsum, row_ofs, rs);
    k_qfill<<<gq, 256, 0, stream>>>(queues, gcur, row_ofs, cur_i, sorted);
    k_prep<<<46, 256, 0, stream>>>(W_enc, W_conv, W_dec, W_s, wbe, wbc, wbd, wbs);

    const int GB = (NN + 63) / 64;   // 782
    for (int m = 0; m < MM; m++) {
        k_encconv<<<GB, 256, 0, stream>>>(x, wbe + (size_t)m * 2048 * 8,
                                          b_enc + (size_t)m * 2 * 64,
                                          wbc + (size_t)m * 1024 * 8, xw_buf);
        k_gather<<<(NN + 3) / 4, 256, 0, stream>>>(sorted + (size_t)m * EE,
                                                   row_ofs + (size_t)m * (NN + 1),
                                                   rs + (size_t)m * NN, xw_buf, gg_buf);
        k_post<<<GB, 256, 0, stream>>>(gg_buf, xw_buf, rs + (size_t)m * NN,
                                       b_conv + (size_t)m * 2 * 64,
                                       wbd + (size_t)m * 512 * 8,
                                       b_dec + (size_t)m * 2 * 32,
                                       wbs, b_s, qv,
                                       z_buf + (size_t)m * NN * 64, score, m);
    }
    k_beta<<<1, 64, 0, stream>>>(score, beta_ws, out);
    k_out<<<GB, 256, 0, stream>>>(z_buf, beta_ws, W_o, b_o, out);
}

// Round 6
// 641.365 us; speedup vs baseline: 1.0672x; 1.0672x over previous
//
#include <hip/hip_runtime.h>

#define NN 50000
#define EE 800000
#define MM 3
#define HH 2
#define IND 128
#define HIDD 64
#define HEADD 32
#define OUTD 16
#define ATTD 128

#define NPART 8
#define PSZ 6250

#define NB4 12500          // NN/4 int4 groups per metapath
#define SB 49              // scan blocks per metapath

#define NG4 200000         // EE/4 int4 groups per metapath
#define BBLK 196           // bucket blocks per metapath (196*1024 >= 200000)
#define QCAP 105000        // queue capacity per (m,part)
#define QSUB 16            // sub-blocks per (m,part) in qdeg/qfill

typedef unsigned short u16;
typedef unsigned long long u64;
typedef short bf16x8 __attribute__((ext_vector_type(8)));
typedef unsigned short u16x8 __attribute__((ext_vector_type(8)));
typedef float f32x4 __attribute__((ext_vector_type(4)));

__device__ __forceinline__ float lrelu(float v) { return v > 0.f ? v : 0.1f * v; }

__device__ __forceinline__ float fast_tanh(float x) {
    float ax = fabsf(x);
    float e = __expf(-2.0f * ax);
    float t = (1.0f - e) * __builtin_amdgcn_rcpf(1.0f + e);
    return copysignf(t, x);
}

__device__ __forceinline__ u16 f2b(float f) {          // fp32 -> bf16 RNE
    union { float f; unsigned int u; } v; v.f = f;
    unsigned int r = v.u + 0x7fffu + ((v.u >> 16) & 1u);
    return (u16)(r >> 16);
}
__device__ __forceinline__ float b2f(u16 u) {
    union { unsigned int u; float f; } v; v.u = ((unsigned int)u) << 16; return v.f;
}

// ================= phase A: bucket edges by dst-part (single read of ei) =================
// queue entries packed (dst<<32)|src, streamed to HBM with nontemporal stores so the
// dirty lines never occupy L2 (they'd evict k_qfill's partially-filled CSR lines).
__global__ __launch_bounds__(256) void k_bucket(const int* __restrict__ ei,
                                                u64* __restrict__ queues,
                                                int* __restrict__ gcur) {
    __shared__ int cnt[NPART];
    __shared__ int base[NPART];
    const int m = blockIdx.y, tid = threadIdx.x;
    const int4* s4 = (const int4*)(ei + (size_t)m * 2 * EE);
    const int4* d4 = (const int4*)(ei + (size_t)m * 2 * EE + EE);
    const int q0 = blockIdx.x * 1024;
    if (tid < NPART) cnt[tid] = 0;
    __syncthreads();
#pragma unroll
    for (int i = 0; i < 4; i++) {
        int q = q0 + i * 256 + tid;
        if (q < NG4) {
            int4 dv = d4[q];
            atomicAdd(&cnt[dv.x / PSZ], 1);
            atomicAdd(&cnt[dv.y / PSZ], 1);
            atomicAdd(&cnt[dv.z / PSZ], 1);
            atomicAdd(&cnt[dv.w / PSZ], 1);
        }
    }
    __syncthreads();
    if (tid < NPART) { base[tid] = atomicAdd(&gcur[m * NPART + tid], cnt[tid]); cnt[tid] = 0; }
    __syncthreads();
#pragma unroll
    for (int i = 0; i < 4; i++) {
        int q = q0 + i * 256 + tid;
        if (q < NG4) {
            int4 dv = d4[q];
            int4 sv = s4[q];
            int ds[4] = {dv.x, dv.y, dv.z, dv.w};
            int ss[4] = {sv.x, sv.y, sv.z, sv.w};
#pragma unroll
            for (int e = 0; e < 4; e++) {
                int p = ds[e] / PSZ;
                int slot = base[p] + atomicAdd(&cnt[p], 1);
                if (slot < QCAP) {
                    u64 pk = ((u64)(unsigned)ds[e] << 32) | (unsigned)ss[e];
                    __builtin_nontemporal_store(pk, &queues[((size_t)(m * NPART + p)) * QCAP + slot]);
                }
            }
        }
    }
}

// ================= phase B: degree count from own queue (XCD-pinned part) =================
// normal loads: warms clean L2 lines for k_qfill (clean lines evict silently).
__global__ __launch_bounds__(256) void k_qdeg(const u64* __restrict__ queues,
                                              const int* __restrict__ gcur,
                                              int* __restrict__ deg) {
    const int m = blockIdx.y;
    const int p = blockIdx.x & 7, sub = blockIdx.x >> 3;
    int qlen = gcur[m * NPART + p];
    if (qlen > QCAP) qlen = QCAP;
    const int per = (qlen + QSUB - 1) / QSUB;
    const int beg = sub * per;
    const int end = min(beg + per, qlen);
    const u64* q = queues + ((size_t)(m * NPART + p)) * QCAP;
    int* dg = deg + m * NN;
    for (int i = beg + threadIdx.x; i < end; i += 256) {
        int d = (int)(q[i] >> 32);
        atomicAdd(&dg[d], 1);
    }
}

// ---- scan phase 1: per-block sums of 1024 degrees ----
__global__ __launch_bounds__(256) void k_scan1(const int* __restrict__ deg, int* __restrict__ bsum) {
    __shared__ int wsum[4];
    const int m = blockIdx.y, b = blockIdx.x, tid = threadIdx.x;
    const int4* d4 = (const int4*)(deg + (size_t)m * NN);
    int idx4 = b * 256 + tid;
    int s = 0;
    if (idx4 < NB4) { int4 v = d4[idx4]; s = v.x + v.y + v.z + v.w; }
    const int lane = tid & 63, w = tid >> 6;
    int v = s;
    for (int off = 1; off < 64; off <<= 1) { int t = __shfl_up(v, off); if (lane >= off) v += t; }
    if (lane == 63) wsum[w] = v;
    __syncthreads();
    if (tid == 0) bsum[m * SB + b] = wsum[0] + wsum[1] + wsum[2] + wsum[3];
}

// ---- scan phase 2: exclusive scan of the 3x49 block sums (in place) ----
__global__ __launch_bounds__(256) void k_scan2(int* __restrict__ bsum) {
    __shared__ int ld[MM * SB];
    const int tid = threadIdx.x;
    if (tid < MM * SB) ld[tid] = bsum[tid];
    __syncthreads();
    if (tid < MM) {
        int run = 0;
        for (int b = 0; b < SB; b++) { int t = ld[tid * SB + b]; ld[tid * SB + b] = run; run += t; }
    }
    __syncthreads();
    if (tid < MM * SB) bsum[tid] = ld[tid];
}

// ---- scan phase 3: intra-block scan + write ofs (exclusive) + rs ----
__global__ __launch_bounds__(256) void k_scan3(const int* __restrict__ deg, const int* __restrict__ bsum,
                                               int* __restrict__ ofs, float* __restrict__ rs) {
    __shared__ int wsum[4];
    const int m = blockIdx.y, b = blockIdx.x, tid = threadIdx.x;
    const int4* d4 = (const int4*)(deg + (size_t)m * NN);
    int* o = ofs + (size_t)m * (NN + 1);
    float* r = rs + (size_t)m * NN;
    int idx4 = b * 256 + tid;
    int4 dv = make_int4(0, 0, 0, 0);
    if (idx4 < NB4) dv = d4[idx4];
    int s = dv.x + dv.y + dv.z + dv.w;
    const int lane = tid & 63, w = tid >> 6;
    int v = s;
    for (int off = 1; off < 64; off <<= 1) { int t = __shfl_up(v, off); if (lane >= off) v += t; }
    if (lane == 63) wsum[w] = v;
    __syncthreads();
    int wexcl = 0;
    for (int j = 0; j < 4; j++) if (j < w) wexcl += wsum[j];
    int base = bsum[m * SB + b] + wexcl + (v - s);
    if (idx4 < NB4) {
        int e0 = base, e1 = e0 + dv.x, e2 = e1 + dv.y, e3 = e2 + dv.z;
        ((int4*)o)[idx4] = make_int4(e0, e1, e2, e3);
        float4 rv;
        rv.x = rsqrtf((float)(dv.x + 1));
        rv.y = rsqrtf((float)(dv.y + 1));
        rv.z = rsqrtf((float)(dv.z + 1));
        rv.w = rsqrtf((float)(dv.w + 1));
        ((float4*)r)[idx4] = rv;
    }
    if (b == SB - 1 && tid == 0) o[NN] = EE;
}

// ================= phase C: CSR fill from own queue (XCD-pinned part) =================
// nontemporal queue loads: hit the clean lines qdeg left, never allocate on miss —
// the only dirty L2 set is the part's 400 KB srt window, which stays resident.
__global__ __launch_bounds__(256) void k_qfill(const u64* __restrict__ queues,
                                               const int* __restrict__ gcur,
                                               const int* __restrict__ ofs,
                                               int* __restrict__ cur,
                                               int* __restrict__ sorted) {
    const int m = blockIdx.y;
    const int p = blockIdx.x & 7, sub = blockIdx.x >> 3;
    int qlen = gcur[m * NPART + p];
    if (qlen > QCAP) qlen = QCAP;
    const int per = (qlen + QSUB - 1) / QSUB;
    const int beg = sub * per;
    const int end = min(beg + per, qlen);
    const u64* q = queues + ((size_t)(m * NPART + p)) * QCAP;
    const int* of = ofs + (size_t)m * (NN + 1);
    int* cu = cur + (size_t)m * NN;
    int* srt = sorted + (size_t)m * EE;
    for (int i = beg + threadIdx.x; i < end; i += 256) {
        u64 e = __builtin_nontemporal_load(&q[i]);
        int src = (int)(e & 0xffffffffu);
        int dst = (int)(e >> 32);
        int pos = of[dst] + atomicAdd(&cu[dst], 1);
        srt[pos] = src;
    }
}

// ================= weight prep: fp32 -> bf16 MFMA B-fragment layout =================
__global__ __launch_bounds__(256) void k_prep(const float* __restrict__ We, const float* __restrict__ Wc,
                                              const float* __restrict__ Wd, const float* __restrict__ Ws,
                                              u16* __restrict__ wbe, u16* __restrict__ wbc,
                                              u16* __restrict__ wbd, u16* __restrict__ wbs) {
    int t = blockIdx.x * 256 + threadIdx.x;
    if (t >= 11776) return;
    bf16x8 val;
    u16* dst;
    if (t < 6144) {                       // enc: per m, 8 nt x 4 ks x 64 lanes, K=128, N=128
        int m = t >> 11, r = t & 2047;
        int nt = r >> 8, ks = (r >> 6) & 3, lane = r & 63;
        int n = nt * 16 + (lane & 15), h = n >> 6, o = n & 63;
        int kb = ks * 32 + (lane >> 4) * 8;
        const float* w = We + ((size_t)(m * 2 + h) * 128) * 64;
#pragma unroll
        for (int j = 0; j < 8; j++) val[j] = (short)f2b(w[(size_t)(kb + j) * 64 + o]);
        dst = wbe + ((size_t)m * 2048 + r) * 8;
    } else if (t < 9216) {                // conv: per m, 8 nt x 2 ks, K=64, N=128 (head-blockdiag)
        int u = t - 6144;
        int m = u >> 10, r = u & 1023;
        int nt = r >> 7, ks = (r >> 6) & 1, lane = r & 63;
        int h = nt >> 2, o = (nt & 3) * 16 + (lane & 15);
        int kb = ks * 32 + (lane >> 4) * 8;
        const float* w = Wc + ((size_t)(m * 2 + h) * 64) * 64;
#pragma unroll
        for (int j = 0; j < 8; j++) val[j] = (short)f2b(w[(size_t)(kb + j) * 64 + o]);
        dst = wbc + ((size_t)m * 1024 + r) * 8;
    } else if (t < 10752) {               // dec: per m, 4 nt x 2 ks, K=64, N=64 (head-blockdiag)
        int u = t - 9216;
        int m = u >> 9, r = u & 511;
        int nt = r >> 7, ks = (r >> 6) & 1, lane = r & 63;
        int h = nt >> 1, o = (nt & 1) * 16 + (lane & 15);
        int kb = ks * 32 + (lane >> 4) * 8;
        const float* w = Wd + ((size_t)(m * 2 + h) * 64) * 32;
#pragma unroll
        for (int j = 0; j < 8; j++) val[j] = (short)f2b(w[(size_t)(kb + j) * 32 + o]);
        dst = wbd + ((size_t)m * 512 + r) * 8;
    } else {                              // W_s: 8 nt x 2 ks, K=64, N=128
        int r = t - 10752;
        int nt = r >> 7, ks = (r >> 6) & 1, lane = r & 63;
        int n = nt * 16 + (lane & 15);
        int kb = ks * 32 + (lane >> 4) * 8;
#pragma unroll
        for (int j = 0; j < 8; j++) val[j] = (short)f2b(Ws[(size_t)(kb + j) * 128 + n]);
        dst = wbs + (size_t)r * 8;
    }
    *(bf16x8*)dst = val;
}

// ================= fused enc+conv: xw = (lrelu(x@We+be)) @ Wc, h tile via LDS =================
#define HLS 133   // fp32 row stride: 5*r mod 32 -> 2 lanes/bank (free)
__global__ __launch_bounds__(256) void k_encconv(const float* __restrict__ x,
                                                 const u16* __restrict__ wbe,
                                                 const float* __restrict__ be,
                                                 const u16* __restrict__ wbc,
                                                 u16* __restrict__ xw) {
    __shared__ float hl[64 * HLS];
    const int tid = threadIdx.x, lane = tid & 63, wave = tid >> 6;
    const int quad = lane >> 4, c16 = lane & 15;
    const int row = blockIdx.x * 64 + wave * 16 + c16;
    const bool ok = row < NN;
    const bf16x8* wbE = (const bf16x8*)wbe;
    f32x4 zero = {0.f, 0.f, 0.f, 0.f};
    f32x4 acc[8];
#pragma unroll
    for (int nt = 0; nt < 8; nt++) acc[nt] = zero;
#pragma unroll
    for (int ks = 0; ks < 4; ks++) {
        bf16x8 a = {0, 0, 0, 0, 0, 0, 0, 0};
        if (ok) {
            const float* xp = x + (size_t)row * 128 + ks * 32 + quad * 8;
            float4 xa = *(const float4*)xp;
            float4 xb = *(const float4*)(xp + 4);
            a[0] = (short)f2b(xa.x); a[1] = (short)f2b(xa.y);
            a[2] = (short)f2b(xa.z); a[3] = (short)f2b(xa.w);
            a[4] = (short)f2b(xb.x); a[5] = (short)f2b(xb.y);
            a[6] = (short)f2b(xb.z); a[7] = (short)f2b(xb.w);
        }
#pragma unroll
        for (int nt = 0; nt < 8; nt++)
            acc[nt] = __builtin_amdgcn_mfma_f32_16x16x32_bf16(a, wbE[(nt * 4 + ks) * 64 + lane], acc[nt], 0, 0, 0);
    }
    const int rbl = wave * 16 + quad * 4;
#pragma unroll
    for (int nt = 0; nt < 8; nt++) {
        int col = nt * 16 + c16, hh = col >> 6, o = col & 63;
        float bias = be[hh * 64 + o];
#pragma unroll
        for (int j = 0; j < 4; j++) {
            int rl = rbl + j;
            int rg = blockIdx.x * 64 + rl;
            hl[rl * HLS + col] = (rg < NN) ? lrelu(acc[nt][j] + bias) : 0.f;
        }
    }
    __syncthreads();
    const bf16x8* wbC = (const bf16x8*)wbc;
    f32x4 cacc[8];
#pragma unroll
    for (int nt = 0; nt < 8; nt++) cacc[nt] = zero;
    const int rl = wave * 16 + c16;
#pragma unroll
    for (int ks = 0; ks < 2; ks++) {
        bf16x8 a0, a1;
        const float* hp = &hl[rl * HLS + ks * 32 + quad * 8];
#pragma unroll
        for (int j = 0; j < 8; j++) { a0[j] = (short)f2b(hp[j]); a1[j] = (short)f2b(hp[64 + j]); }
#pragma unroll
        for (int nt = 0; nt < 8; nt++)
            cacc[nt] = __builtin_amdgcn_mfma_f32_16x16x32_bf16(nt < 4 ? a0 : a1, wbC[(nt * 2 + ks) * 64 + lane], cacc[nt], 0, 0, 0);
    }
#pragma unroll
    for (int nt = 0; nt < 8; nt++) {
        int col = nt * 16 + c16;
#pragma unroll
        for (int j = 0; j < 4; j++) {
            int r = blockIdx.x * 64 + rbl + j;
            if (r < NN) xw[(size_t)r * 128 + col] = f2b(cacc[nt][j]);
        }
    }
}

// ================= gather: gg[dst] = rs[dst] * sum_src rs[src]*xw[src] =================
// 4 edges in flight per wave (16 lanes x ushort8 covers the 256 B row)
__global__ __launch_bounds__(256) void k_gather(const int* __restrict__ sorted,
                                                const int* __restrict__ ofs,
                                                const float* __restrict__ rs,
                                                const u16* __restrict__ xw,
                                                u16* __restrict__ gg) {
    const int tid = threadIdx.x;
    const int dst = blockIdx.x * 4 + (tid >> 6);
    if (dst >= NN) return;
    const int lane = tid & 63, p = lane >> 4, c = lane & 15;
    int beg = ofs[dst], end = ofs[dst + 1];
    float acc[8] = {0.f, 0.f, 0.f, 0.f, 0.f, 0.f, 0.f, 0.f};
    for (int j = beg + p; j < end; j += 4) {
        int s = sorted[j];
        float cf = rs[s];
        u16x8 v = *(const u16x8*)&xw[(size_t)s * 128 + c * 8];
#pragma unroll
        for (int k = 0; k < 8; k++) acc[k] = fmaf(cf, b2f(v[k]), acc[k]);
    }
#pragma unroll
    for (int k = 0; k < 8; k++) {
        acc[k] += __shfl_down(acc[k], 16);
        acc[k] += __shfl_down(acc[k], 32);
    }
    if (p == 0) {
        float rsd = rs[dst];
        u16x8 o;
#pragma unroll
        for (int k = 0; k < 8; k++) o[k] = f2b(acc[k] * rsd);
        *(u16x8*)&gg[(size_t)dst * 128 + c * 8] = o;
    }
}

// ================= post+score =================
__global__ __launch_bounds__(256) void k_post(const u16* __restrict__ gg,
                                              const u16* __restrict__ xw,
                                              const float* __restrict__ rs,
                                              const float* __restrict__ bconv,
                                              const u16* __restrict__ wbd,
                                              const float* __restrict__ bdec,
                                              const u16* __restrict__ wbs,
                                              const float* __restrict__ bs,
                                              const float* __restrict__ qv,
                                              float* __restrict__ z,
                                              float* __restrict__ score, int m) {
    __shared__ float zl[64 * 68];
    const int tid = threadIdx.x, lane = tid & 63, wave = tid >> 6;
    const int quad = lane >> 4, c16 = lane & 15;
    const int row = blockIdx.x * 64 + wave * 16 + c16;
    const bool ok = row < NN;
    float rs2 = 0.f;
    if (ok) { float t = rs[row]; rs2 = t * t; }
    const bf16x8* wd = (const bf16x8*)wbd;
    f32x4 acc[4];
    f32x4 zero = {0.f, 0.f, 0.f, 0.f};
#pragma unroll
    for (int nt = 0; nt < 4; nt++) acc[nt] = zero;
#pragma unroll
    for (int ks = 0; ks < 2; ks++) {
        bf16x8 a0 = {0,0,0,0,0,0,0,0}, a1 = {0,0,0,0,0,0,0,0};
        if (ok) {
            int k0 = ks * 32 + quad * 8;
            const u16* gp0 = &gg[(size_t)row * 128 + k0];
            const u16* xp0 = &xw[(size_t)row * 128 + k0];
            const u16* gp1 = gp0 + 64;
            const u16* xp1 = xp0 + 64;
#pragma unroll
            for (int j = 0; j < 8; j++) {
                float v0 = lrelu(fmaf(b2f(xp0[j]), rs2, b2f(gp0[j])) + bconv[k0 + j]);
                float v1 = lrelu(fmaf(b2f(xp1[j]), rs2, b2f(gp1[j])) + bconv[64 + k0 + j]);
                a0[j] = (short)f2b(v0);
                a1[j] = (short)f2b(v1);
            }
        }
#pragma unroll
        for (int nt = 0; nt < 4; nt++)
            acc[nt] = __builtin_amdgcn_mfma_f32_16x16x32_bf16(nt < 2 ? a0 : a1, wd[(nt * 2 + ks) * 64 + lane], acc[nt], 0, 0, 0);
    }
    const int rbl = wave * 16 + quad * 4;
#pragma unroll
    for (int nt = 0; nt < 4; nt++) {
        int col = nt * 16 + c16, hh = col >> 5, o = col & 31;
        float bias = bdec[hh * 32 + o];
#pragma unroll
        for (int j = 0; j < 4; j++) {
            int rl = rbl + j;
            int rg = blockIdx.x * 64 + rl;
            zl[rl * 68 + col] = (rg < NN) ? (acc[nt][j] + bias) : 0.f;
        }
    }
    __syncthreads();
    {
        int rl = tid >> 2, cq = tid & 3;
        int rg = blockIdx.x * 64 + rl;
        if (rg < NN) {
#pragma unroll
            for (int i = 0; i < 4; i++) {
                int c4 = (cq * 4 + i) * 4;
                *(float4*)&z[(size_t)rg * 64 + c4] = *(const float4*)&zl[rl * 68 + c4];
            }
        }
    }
    const bf16x8* wsb = (const bf16x8*)wbs;
    f32x4 sa[8];
#pragma unroll
    for (int nt = 0; nt < 8; nt++) sa[nt] = zero;
#pragma unroll
    for (int ks = 0; ks < 2; ks++) {
        bf16x8 a;
        const float* zp = &zl[(wave * 16 + c16) * 68 + ks * 32 + quad * 8];
#pragma unroll
        for (int j = 0; j < 8; j++) a[j] = (short)f2b(zp[j]);
#pragma unroll
        for (int nt = 0; nt < 8; nt++)
            sa[nt] = __builtin_amdgcn_mfma_f32_16x16x32_bf16(a, wsb[(nt * 2 + ks) * 64 + lane], sa[nt], 0, 0, 0);
    }
    float s = 0.f;
#pragma unroll
    for (int nt = 0; nt < 8; nt++) {
        int col = nt * 16 + c16;
        float qc = qv[col], bb = bs[col];
#pragma unroll
        for (int j = 0; j < 4; j++) {
            int rg = blockIdx.x * 64 + rbl + j;
            if (rg < NN) s += fast_tanh(sa[nt][j] + bb) * qc;
        }
    }
#pragma unroll
    for (int off = 1; off < 64; off <<= 1) s += __shfl_xor(s, off);
    if (lane == 0) atomicAdd(&score[m], s);
}

// ================= beta =================
__global__ void k_beta(const float* __restrict__ score, float* __restrict__ beta_ws,
                       float* __restrict__ out) {
    if (threadIdx.x == 0) {
        float s0 = score[0] / (float)NN, s1 = score[1] / (float)NN, s2 = score[2] / (float)NN;
        float mx = fmaxf(s0, fmaxf(s1, s2));
        float e0 = expf(s0 - mx), e1 = expf(s1 - mx), e2 = expf(s2 - mx);
        float inv = 1.f / (e0 + e1 + e2);
        beta_ws[0] = e0 * inv; beta_ws[1] = e1 * inv; beta_ws[2] = e2 * inv;
        out[800000] = e0 * inv; out[800001] = e1 * inv; out[800002] = e2 * inv;
    }
}

// ================= output =================
__global__ __launch_bounds__(256) void k_out(const float* __restrict__ z,
                                             const float* __restrict__ beta,
                                             const float* __restrict__ Wo,
                                             const float* __restrict__ bo,
                                             float* __restrict__ out) {
    __shared__ float Zt[64 * 68];
    __shared__ float Wl[64 * 16];
    __shared__ float bl[16];
    const int tid = threadIdx.x, nbase = blockIdx.x * 64;
    float b0 = beta[0], b1 = beta[1], b2 = beta[2];
    for (int qq = tid; qq < 64 * 16; qq += 256) {
        int node = qq >> 4, k4 = qq & 15;
        int ng = nbase + node;
        float4 v = make_float4(0.f, 0.f, 0.f, 0.f);
        if (ng < NN) {
            float4 z0 = *(const float4*)&z[((size_t)0 * NN + ng) * 64 + k4 * 4];
            float4 z1 = *(const float4*)&z[((size_t)1 * NN + ng) * 64 + k4 * 4];
            float4 z2 = *(const float4*)&z[((size_t)2 * NN + ng) * 64 + k4 * 4];
            v.x = b0 * z0.x + b1 * z1.x + b2 * z2.x;
            v.y = b0 * z0.y + b1 * z1.y + b2 * z2.y;
            v.z = b0 * z0.z + b1 * z1.z + b2 * z2.z;
            v.w = b0 * z0.w + b1 * z1.w + b2 * z2.w;
        }
        *(float4*)&Zt[node * 68 + k4 * 4] = v;
    }
    for (int qq = tid; qq < 64 * 16 / 4; qq += 256)
        ((float4*)Wl)[qq] = ((const float4*)Wo)[qq];
    if (tid < 16) bl[tid] = bo[tid];
    __syncthreads();

    const int node = tid >> 2, cg = tid & 3;
    float4 a = make_float4(bl[cg * 4 + 0], bl[cg * 4 + 1], bl[cg * 4 + 2], bl[cg * 4 + 3]);
    for (int k = 0; k < 64; k++) {
        float zv = Zt[node * 68 + k];
        float4 w = *(const float4*)&Wl[k * 16 + cg * 4];
        a.x = fmaf(zv, w.x, a.x);
        a.y = fmaf(zv, w.y, a.y);
        a.z = fmaf(zv, w.z, a.z);
        a.w = fmaf(zv, w.w, a.w);
    }
    float mx = fmaxf(fmaxf(a.x, a.y), fmaxf(a.z, a.w));
    mx = fmaxf(mx, __shfl_xor(mx, 1));
    mx = fmaxf(mx, __shfl_xor(mx, 2));
    float sm = expf(a.x - mx) + expf(a.y - mx) + expf(a.z - mx) + expf(a.w - mx);
    sm += __shfl_xor(sm, 1);
    sm += __shfl_xor(sm, 2);
    float lse = mx + logf(sm);
    int ng = nbase + node;
    if (ng < NN) {
        float4 r = make_float4(a.x - lse, a.y - lse, a.z - lse, a.w - lse);
        *(float4*)&out[(size_t)ng * 16 + cg * 4] = r;
    }
}

extern "C" void kernel_launch(void* const* d_in, const int* in_sizes, int n_in,
                              void* d_out, int out_size, void* d_ws, size_t ws_size,
                              hipStream_t stream) {
    const float* x      = (const float*)d_in[0];
    const int*   ei     = (const int*)d_in[1];
    const float* W_enc  = (const float*)d_in[2];
    const float* b_enc  = (const float*)d_in[3];
    const float* W_conv = (const float*)d_in[4];
    const float* b_conv = (const float*)d_in[5];
    const float* W_dec  = (const float*)d_in[6];
    const float* b_dec  = (const float*)d_in[7];
    const float* W_s    = (const float*)d_in[8];
    const float* b_s    = (const float*)d_in[9];
    const float* qv     = (const float*)d_in[10];
    const float* W_o    = (const float*)d_in[11];
    const float* b_o    = (const float*)d_in[12];
    float* out = (float*)d_out;

    char* ws = (char*)d_ws;
    size_t off = 0;
    auto alloc = [&](size_t bytes) -> char* {
        char* p = ws + off;
        off = (off + bytes + 255) & ~(size_t)255;
        return p;
    };
    int*   deg_i   = (int*)alloc((size_t)MM * NN * 4);
    int*   row_ofs = (int*)alloc((size_t)MM * (NN + 1) * 4);
    int*   cur_i   = (int*)alloc((size_t)MM * NN * 4);
    float* rs      = (float*)alloc((size_t)MM * NN * 4);
    int*   sorted  = (int*)alloc((size_t)MM * EE * 4);
    u64*   queues  = (u64*)alloc((size_t)MM * NPART * QCAP * 8);
    int*   gcur    = (int*)alloc((size_t)MM * NPART * 4);
    int*   bsum    = (int*)alloc((size_t)MM * SB * 4);
    float* score   = (float*)alloc(64);
    float* beta_ws = (float*)alloc(64);
    u16*   wbe     = (u16*)alloc((size_t)MM * 2048 * 8 * 2);
    u16*   wbc     = (u16*)alloc((size_t)MM * 1024 * 8 * 2);
    u16*   wbd     = (u16*)alloc((size_t)MM * 512 * 8 * 2);
    u16*   wbs     = (u16*)alloc((size_t)1024 * 8 * 2);
    u16*   xw_buf  = (u16*)alloc((size_t)NN * 128 * 2);
    u16*   gg_buf  = (u16*)alloc((size_t)NN * 128 * 2);
    float* z_buf   = (float*)alloc((size_t)MM * NN * 64 * 4);

    hipMemsetAsync(deg_i, 0, (size_t)MM * NN * 4, stream);
    hipMemsetAsync(cur_i, 0, (size_t)MM * NN * 4, stream);
    hipMemsetAsync(gcur, 0, (size_t)MM * NPART * 4, stream);
    hipMemsetAsync(score, 0, 16, stream);

    dim3 gbkt(BBLK, MM);
    dim3 gq(NPART * QSUB, MM);
    dim3 gscan(SB, MM);
    k_bucket<<<gbkt, 256, 0, stream>>>(ei, queues, gcur);
    k_qdeg<<<gq, 256, 0, stream>>>(queues, gcur, deg_i);
    k_scan1<<<gscan, 256, 0, stream>>>(deg_i, bsum);
    k_scan2<<<1, 256, 0, stream>>>(bsum);
    k_scan3<<<gscan, 256, 0, stream>>>(deg_i, bsum, row_ofs, rs);
    k_qfill<<<gq, 256, 0, stream>>>(queues, gcur, row_ofs, cur_i, sorted);
    k_prep<<<46, 256, 0, stream>>>(W_enc, W_conv, W_dec, W_s, wbe, wbc, wbd, wbs);

    const int GB = (NN + 63) / 64;   // 782
    for (int m = 0; m < MM; m++) {
        k_encconv<<<GB, 256, 0, stream>>>(x, wbe + (size_t)m * 2048 * 8,
                                          b_enc + (size_t)m * 2 * 64,
                                          wbc + (size_t)m * 1024 * 8, xw_buf);
        k_gather<<<(NN + 3) / 4, 256, 0, stream>>>(sorted + (size_t)m * EE,
                                                   row_ofs + (size_t)m * (NN + 1),
                                                   rs + (size_t)m * NN, xw_buf, gg_buf);
        k_post<<<GB, 256, 0, stream>>>(gg_buf, xw_buf, rs + (size_t)m * NN,
                                       b_conv + (size_t)m * 2 * 64,
                                       wbd + (size_t)m * 512 * 8,
                                       b_dec + (size_t)m * 2 * 32,
                                       wbs, b_s, qv,
                                       z_buf + (size_t)m * NN * 64, score, m);
    }
    k_beta<<<1, 64, 0, stream>>>(score, beta_ws, out);
    k_out<<<GB, 256, 0, stream>>>(z_buf, beta_ws, W_o, b_o, out);
}

// Round 7
// 584.101 us; speedup vs baseline: 1.1718x; 1.0980x over previous
//
#include <hip/hip_runtime.h>

#define NN 50000
#define EE 800000
#define MM 3
#define HH 2
#define IND 128
#define HIDD 64
#define HEADD 32
#define OUTD 16
#define ATTD 128

#define NPART 8
#define PSZ 6250

#define NG4 200000         // EE/4 int4 groups per metapath
#define BBLK 196           // bucket blocks per metapath
#define QCAP 105000        // queue capacity per (m,part)

#define CSUB 8             // sub-ranges per part in k_csr
#define RSZ 782            // dsts per sub-range (782*8=6256 >= 6250)

typedef unsigned short u16;
typedef unsigned long long u64;
typedef short bf16x8 __attribute__((ext_vector_type(8)));
typedef unsigned short u16x8 __attribute__((ext_vector_type(8)));
typedef float f32x4 __attribute__((ext_vector_type(4)));

__device__ __forceinline__ float lrelu(float v) { return v > 0.f ? v : 0.1f * v; }

__device__ __forceinline__ float fast_tanh(float x) {
    float ax = fabsf(x);
    float e = __expf(-2.0f * ax);
    float t = (1.0f - e) * __builtin_amdgcn_rcpf(1.0f + e);
    return copysignf(t, x);
}

__device__ __forceinline__ u16 f2b(float f) {          // fp32 -> bf16 RNE
    union { float f; unsigned int u; } v; v.f = f;
    unsigned int r = v.u + 0x7fffu + ((v.u >> 16) & 1u);
    return (u16)(r >> 16);
}
__device__ __forceinline__ float b2f(u16 u) {
    union { unsigned int u; float f; } v; v.u = ((unsigned int)u) << 16; return v.f;
}

// ================= phase A: bucket edges by dst-part (single read of ei) =================
__global__ __launch_bounds__(256) void k_bucket(const int* __restrict__ ei,
                                                u64* __restrict__ queues,
                                                int* __restrict__ gcur) {
    __shared__ int cnt[NPART];
    __shared__ int base[NPART];
    const int m = blockIdx.y, tid = threadIdx.x;
    const int4* s4 = (const int4*)(ei + (size_t)m * 2 * EE);
    const int4* d4 = (const int4*)(ei + (size_t)m * 2 * EE + EE);
    const int q0 = blockIdx.x * 1024;
    if (tid < NPART) cnt[tid] = 0;
    __syncthreads();
#pragma unroll
    for (int i = 0; i < 4; i++) {
        int q = q0 + i * 256 + tid;
        if (q < NG4) {
            int4 dv = d4[q];
            atomicAdd(&cnt[dv.x / PSZ], 1);
            atomicAdd(&cnt[dv.y / PSZ], 1);
            atomicAdd(&cnt[dv.z / PSZ], 1);
            atomicAdd(&cnt[dv.w / PSZ], 1);
        }
    }
    __syncthreads();
    if (tid < NPART) { base[tid] = atomicAdd(&gcur[m * NPART + tid], cnt[tid]); cnt[tid] = 0; }
    __syncthreads();
#pragma unroll
    for (int i = 0; i < 4; i++) {
        int q = q0 + i * 256 + tid;
        if (q < NG4) {
            int4 dv = d4[q];
            int4 sv = s4[q];
            int ds[4] = {dv.x, dv.y, dv.z, dv.w};
            int ss[4] = {sv.x, sv.y, sv.z, sv.w};
#pragma unroll
            for (int e = 0; e < 4; e++) {
                int p = ds[e] / PSZ;
                int slot = base[p] + atomicAdd(&cnt[p], 1);
                if (slot < QCAP) {
                    u64 pk = ((u64)(unsigned)ds[e] << 32) | (unsigned)ss[e];
                    __builtin_nontemporal_store(pk, &queues[((size_t)(m * NPART + p)) * QCAP + slot]);
                }
            }
        }
    }
}

// ================= part-base scan (24 values) =================
__global__ void k_pscan(const int* __restrict__ gcur, int* __restrict__ pbase) {
    int t = threadIdx.x;
    if (t < MM) {
        int run = 0;
        for (int p = 0; p < NPART; p++) {
            int L = gcur[t * NPART + p]; if (L > QCAP) L = QCAP;
            pbase[t * NPART + p] = run; run += L;
        }
    }
}

// ================= CSR build: one block owns one (m, part, 782-dst sub-range) =================
// Pass 1 counts into LDS (plus 'lowc' = edges below the range -> base). LDS scan emits
// ofs + rs for the range; pass 2 re-streams the queue scattering srt via LDS cursors.
// All writes to a given CSR line are issued by this single block within a few microseconds,
// so L2 lines fill completely before writeback (fixes R6's 10x partial-line writeback).
__global__ __launch_bounds__(512) void k_csr(const u64* __restrict__ queues,
                                             const int* __restrict__ gcur,
                                             const int* __restrict__ pbase,
                                             int* __restrict__ ofs,
                                             float* __restrict__ rs,
                                             int* __restrict__ sorted) {
    __shared__ int cnt[RSZ];
    __shared__ int wred[8];
    __shared__ int wscan[8];
    __shared__ int base_s;
    const int m = blockIdx.y;
    const int p = blockIdx.x & 7;
    const int r = blockIdx.x >> 3;
    const int tid = threadIdx.x;
    const int lane = tid & 63, w = tid >> 6;
    int qlen = gcur[m * NPART + p]; if (qlen > QCAP) qlen = QCAP;
    const u64* q = queues + ((size_t)(m * NPART + p)) * QCAP;
    const int relo = r * RSZ;                       // range start within part
    const int dlo = p * PSZ + relo;                 // global dst range start
    const int nd = min(dlo + RSZ, (p + 1) * PSZ) - dlo;
    for (int i = tid; i < RSZ; i += 512) cnt[i] = 0;
    __syncthreads();
    // pass 1: count own range; count edges below range for base
    int lowc = 0;
    for (int i = tid; i < qlen; i += 512) {
        int dst = (int)(q[i] >> 32);
        int rel = dst - p * PSZ;
        lowc += (rel < relo);
        unsigned rr = (unsigned)(rel - relo);
        if (rr < (unsigned)nd) atomicAdd(&cnt[rr], 1);
    }
    for (int off = 32; off; off >>= 1) lowc += __shfl_down(lowc, off);
    if (lane == 0) wred[w] = lowc;
    __syncthreads();
    if (tid == 0) {
        int b = pbase[m * NPART + p];
        for (int j = 0; j < 8; j++) b += wred[j];
        base_s = b;
    }
    __syncthreads();
    // exclusive scan of cnt (2 elems/thread)
    const int c0 = tid * 2;
    int v0 = (c0 < RSZ) ? cnt[c0] : 0;
    int v1 = (c0 + 1 < RSZ) ? cnt[c0 + 1] : 0;
    int s = v0 + v1;
    int vv = s;
    for (int off = 1; off < 64; off <<= 1) { int t = __shfl_up(vv, off); if (lane >= off) vv += t; }
    if (lane == 63) wscan[w] = vv;
    __syncthreads();
    if (tid == 0) { int run = 0; for (int j = 0; j < 8; j++) { int t = wscan[j]; wscan[j] = run; run += t; } }
    __syncthreads();
    int excl = wscan[w] + vv - s;
    int g0 = base_s + excl;
    int g1 = g0 + v0;
    if (c0 < nd) {
        ofs[(size_t)m * (NN + 1) + dlo + c0] = g0;
        rs[(size_t)m * NN + dlo + c0] = rsqrtf((float)(v0 + 1));
    }
    if (c0 + 1 < nd) {
        ofs[(size_t)m * (NN + 1) + dlo + c0 + 1] = g1;
        rs[(size_t)m * NN + dlo + c0 + 1] = rsqrtf((float)(v1 + 1));
    }
    if (p == NPART - 1 && r == CSUB - 1 && tid == 0)
        ofs[(size_t)m * (NN + 1) + NN] = EE;
    __syncthreads();
    if (c0 < RSZ) cnt[c0] = g0;
    if (c0 + 1 < RSZ) cnt[c0 + 1] = g1;
    __syncthreads();
    // pass 2: scatter via LDS cursors (queue is L2-warm from pass 1)
    int* srt = sorted + (size_t)m * EE;
    for (int i = tid; i < qlen; i += 512) {
        u64 e = q[i];
        int dst = (int)(e >> 32);
        unsigned rr = (unsigned)(dst - p * PSZ - relo);
        if (rr < (unsigned)nd) {
            int pos = atomicAdd(&cnt[rr], 1);
            srt[pos] = (int)(e & 0xffffffffu);
        }
    }
}

// ================= weight prep: fp32 -> bf16 MFMA B-fragment layout =================
__global__ __launch_bounds__(256) void k_prep(const float* __restrict__ We, const float* __restrict__ Wc,
                                              const float* __restrict__ Wd, const float* __restrict__ Ws,
                                              u16* __restrict__ wbe, u16* __restrict__ wbc,
                                              u16* __restrict__ wbd, u16* __restrict__ wbs) {
    int t = blockIdx.x * 256 + threadIdx.x;
    if (t >= 11776) return;
    bf16x8 val;
    u16* dst;
    if (t < 6144) {                       // enc: per m, 8 nt x 4 ks x 64 lanes, K=128, N=128
        int m = t >> 11, r = t & 2047;
        int nt = r >> 8, ks = (r >> 6) & 3, lane = r & 63;
        int n = nt * 16 + (lane & 15), h = n >> 6, o = n & 63;
        int kb = ks * 32 + (lane >> 4) * 8;
        const float* w = We + ((size_t)(m * 2 + h) * 128) * 64;
#pragma unroll
        for (int j = 0; j < 8; j++) val[j] = (short)f2b(w[(size_t)(kb + j) * 64 + o]);
        dst = wbe + ((size_t)m * 2048 + r) * 8;
    } else if (t < 9216) {                // conv: per m, 8 nt x 2 ks, K=64, N=128 (head-blockdiag)
        int u = t - 6144;
        int m = u >> 10, r = u & 1023;
        int nt = r >> 7, ks = (r >> 6) & 1, lane = r & 63;
        int h = nt >> 2, o = (nt & 3) * 16 + (lane & 15);
        int kb = ks * 32 + (lane >> 4) * 8;
        const float* w = Wc + ((size_t)(m * 2 + h) * 64) * 64;
#pragma unroll
        for (int j = 0; j < 8; j++) val[j] = (short)f2b(w[(size_t)(kb + j) * 64 + o]);
        dst = wbc + ((size_t)m * 1024 + r) * 8;
    } else if (t < 10752) {               // dec: per m, 4 nt x 2 ks, K=64, N=64 (head-blockdiag)
        int u = t - 9216;
        int m = u >> 9, r = u & 511;
        int nt = r >> 7, ks = (r >> 6) & 1, lane = r & 63;
        int h = nt >> 1, o = (nt & 1) * 16 + (lane & 15);
        int kb = ks * 32 + (lane >> 4) * 8;
        const float* w = Wd + ((size_t)(m * 2 + h) * 64) * 32;
#pragma unroll
        for (int j = 0; j < 8; j++) val[j] = (short)f2b(w[(size_t)(kb + j) * 32 + o]);
        dst = wbd + ((size_t)m * 512 + r) * 8;
    } else {                              // W_s: 8 nt x 2 ks, K=64, N=128
        int r = t - 10752;
        int nt = r >> 7, ks = (r >> 6) & 1, lane = r & 63;
        int n = nt * 16 + (lane & 15);
        int kb = ks * 32 + (lane >> 4) * 8;
#pragma unroll
        for (int j = 0; j < 8; j++) val[j] = (short)f2b(Ws[(size_t)(kb + j) * 128 + n]);
        dst = wbs + (size_t)r * 8;
    }
    *(bf16x8*)dst = val;
}

// ================= fused enc+conv: xw = (lrelu(x@We+be)) @ Wc, h tile via LDS =================
#define HLS 133   // fp32 row stride: 5*r mod 32 -> 2 lanes/bank (free)
__global__ __launch_bounds__(256) void k_encconv(const float* __restrict__ x,
                                                 const u16* __restrict__ wbe,
                                                 const float* __restrict__ be,
                                                 const u16* __restrict__ wbc,
                                                 u16* __restrict__ xw) {
    __shared__ float hl[64 * HLS];
    const int tid = threadIdx.x, lane = tid & 63, wave = tid >> 6;
    const int quad = lane >> 4, c16 = lane & 15;
    const int row = blockIdx.x * 64 + wave * 16 + c16;
    const bool ok = row < NN;
    const bf16x8* wbE = (const bf16x8*)wbe;
    f32x4 zero = {0.f, 0.f, 0.f, 0.f};
    f32x4 acc[8];
#pragma unroll
    for (int nt = 0; nt < 8; nt++) acc[nt] = zero;
#pragma unroll
    for (int ks = 0; ks < 4; ks++) {
        bf16x8 a = {0, 0, 0, 0, 0, 0, 0, 0};
        if (ok) {
            const float* xp = x + (size_t)row * 128 + ks * 32 + quad * 8;
            float4 xa = *(const float4*)xp;
            float4 xb = *(const float4*)(xp + 4);
            a[0] = (short)f2b(xa.x); a[1] = (short)f2b(xa.y);
            a[2] = (short)f2b(xa.z); a[3] = (short)f2b(xa.w);
            a[4] = (short)f2b(xb.x); a[5] = (short)f2b(xb.y);
            a[6] = (short)f2b(xb.z); a[7] = (short)f2b(xb.w);
        }
#pragma unroll
        for (int nt = 0; nt < 8; nt++)
            acc[nt] = __builtin_amdgcn_mfma_f32_16x16x32_bf16(a, wbE[(nt * 4 + ks) * 64 + lane], acc[nt], 0, 0, 0);
    }
    const int rbl = wave * 16 + quad * 4;
#pragma unroll
    for (int nt = 0; nt < 8; nt++) {
        int col = nt * 16 + c16, hh = col >> 6, o = col & 63;
        float bias = be[hh * 64 + o];
#pragma unroll
        for (int j = 0; j < 4; j++) {
            int rl = rbl + j;
            int rg = blockIdx.x * 64 + rl;
            hl[rl * HLS + col] = (rg < NN) ? lrelu(acc[nt][j] + bias) : 0.f;
        }
    }
    __syncthreads();
    const bf16x8* wbC = (const bf16x8*)wbc;
    f32x4 cacc[8];
#pragma unroll
    for (int nt = 0; nt < 8; nt++) cacc[nt] = zero;
    const int rl = wave * 16 + c16;
#pragma unroll
    for (int ks = 0; ks < 2; ks++) {
        bf16x8 a0, a1;
        const float* hp = &hl[rl * HLS + ks * 32 + quad * 8];
#pragma unroll
        for (int j = 0; j < 8; j++) { a0[j] = (short)f2b(hp[j]); a1[j] = (short)f2b(hp[64 + j]); }
#pragma unroll
        for (int nt = 0; nt < 8; nt++)
            cacc[nt] = __builtin_amdgcn_mfma_f32_16x16x32_bf16(nt < 4 ? a0 : a1, wbC[(nt * 2 + ks) * 64 + lane], cacc[nt], 0, 0, 0);
    }
#pragma unroll
    for (int nt = 0; nt < 8; nt++) {
        int col = nt * 16 + c16;
#pragma unroll
        for (int j = 0; j < 4; j++) {
            int r = blockIdx.x * 64 + rbl + j;
            if (r < NN) xw[(size_t)r * 128 + col] = f2b(cacc[nt][j]);
        }
    }
}

// ================= gather: gg[dst] = rs[dst] * sum_src rs[src]*xw[src] =================
__global__ __launch_bounds__(256) void k_gather(const int* __restrict__ sorted,
                                                const int* __restrict__ ofs,
                                                const float* __restrict__ rs,
                                                const u16* __restrict__ xw,
                                                u16* __restrict__ gg) {
    const int tid = threadIdx.x;
    const int dst = blockIdx.x * 4 + (tid >> 6);
    if (dst >= NN) return;
    const int lane = tid & 63, p = lane >> 4, c = lane & 15;
    int beg = ofs[dst], end = ofs[dst + 1];
    float acc[8] = {0.f, 0.f, 0.f, 0.f, 0.f, 0.f, 0.f, 0.f};
    for (int j = beg + p; j < end; j += 4) {
        int s = sorted[j];
        float cf = rs[s];
        u16x8 v = *(const u16x8*)&xw[(size_t)s * 128 + c * 8];
#pragma unroll
        for (int k = 0; k < 8; k++) acc[k] = fmaf(cf, b2f(v[k]), acc[k]);
    }
#pragma unroll
    for (int k = 0; k < 8; k++) {
        acc[k] += __shfl_down(acc[k], 16);
        acc[k] += __shfl_down(acc[k], 32);
    }
    if (p == 0) {
        float rsd = rs[dst];
        u16x8 o;
#pragma unroll
        for (int k = 0; k < 8; k++) o[k] = f2b(acc[k] * rsd);
        *(u16x8*)&gg[(size_t)dst * 128 + c * 8] = o;
    }
}

// ================= post+score =================
__global__ __launch_bounds__(256) void k_post(const u16* __restrict__ gg,
                                              const u16* __restrict__ xw,
                                              const float* __restrict__ rs,
                                              const float* __restrict__ bconv,
                                              const u16* __restrict__ wbd,
                                              const float* __restrict__ bdec,
                                              const u16* __restrict__ wbs,
                                              const float* __restrict__ bs,
                                              const float* __restrict__ qv,
                                              float* __restrict__ z,
                                              float* __restrict__ score, int m) {
    __shared__ float zl[64 * 68];
    const int tid = threadIdx.x, lane = tid & 63, wave = tid >> 6;
    const int quad = lane >> 4, c16 = lane & 15;
    const int row = blockIdx.x * 64 + wave * 16 + c16;
    const bool ok = row < NN;
    float rs2 = 0.f;
    if (ok) { float t = rs[row]; rs2 = t * t; }
    const bf16x8* wd = (const bf16x8*)wbd;
    f32x4 acc[4];
    f32x4 zero = {0.f, 0.f, 0.f, 0.f};
#pragma unroll
    for (int nt = 0; nt < 4; nt++) acc[nt] = zero;
#pragma unroll
    for (int ks = 0; ks < 2; ks++) {
        bf16x8 a0 = {0,0,0,0,0,0,0,0}, a1 = {0,0,0,0,0,0,0,0};
        if (ok) {
            int k0 = ks * 32 + quad * 8;
            const u16* gp0 = &gg[(size_t)row * 128 + k0];
            const u16* xp0 = &xw[(size_t)row * 128 + k0];
            const u16* gp1 = gp0 + 64;
            const u16* xp1 = xp0 + 64;
#pragma unroll
            for (int j = 0; j < 8; j++) {
                float v0 = lrelu(fmaf(b2f(xp0[j]), rs2, b2f(gp0[j])) + bconv[k0 + j]);
                float v1 = lrelu(fmaf(b2f(xp1[j]), rs2, b2f(gp1[j])) + bconv[64 + k0 + j]);
                a0[j] = (short)f2b(v0);
                a1[j] = (short)f2b(v1);
            }
        }
#pragma unroll
        for (int nt = 0; nt < 4; nt++)
            acc[nt] = __builtin_amdgcn_mfma_f32_16x16x32_bf16(nt < 2 ? a0 : a1, wd[(nt * 2 + ks) * 64 + lane], acc[nt], 0, 0, 0);
    }
    const int rbl = wave * 16 + quad * 4;
#pragma unroll
    for (int nt = 0; nt < 4; nt++) {
        int col = nt * 16 + c16, hh = col >> 5, o = col & 31;
        float bias = bdec[hh * 32 + o];
#pragma unroll
        for (int j = 0; j < 4; j++) {
            int rl = rbl + j;
            int rg = blockIdx.x * 64 + rl;
            zl[rl * 68 + col] = (rg < NN) ? (acc[nt][j] + bias) : 0.f;
        }
    }
    __syncthreads();
    {
        int rl = tid >> 2, cq = tid & 3;
        int rg = blockIdx.x * 64 + rl;
        if (rg < NN) {
#pragma unroll
            for (int i = 0; i < 4; i++) {
                int c4 = (cq * 4 + i) * 4;
                *(float4*)&z[(size_t)rg * 64 + c4] = *(const float4*)&zl[rl * 68 + c4];
            }
        }
    }
    const bf16x8* wsb = (const bf16x8*)wbs;
    f32x4 sa[8];
#pragma unroll
    for (int nt = 0; nt < 8; nt++) sa[nt] = zero;
#pragma unroll
    for (int ks = 0; ks < 2; ks++) {
        bf16x8 a;
        const float* zp = &zl[(wave * 16 + c16) * 68 + ks * 32 + quad * 8];
#pragma unroll
        for (int j = 0; j < 8; j++) a[j] = (short)f2b(zp[j]);
#pragma unroll
        for (int nt = 0; nt < 8; nt++)
            sa[nt] = __builtin_amdgcn_mfma_f32_16x16x32_bf16(a, wsb[(nt * 2 + ks) * 64 + lane], sa[nt], 0, 0, 0);
    }
    float s = 0.f;
#pragma unroll
    for (int nt = 0; nt < 8; nt++) {
        int col = nt * 16 + c16;
        float qc = qv[col], bb = bs[col];
#pragma unroll
        for (int j = 0; j < 4; j++) {
            int rg = blockIdx.x * 64 + rbl + j;
            if (rg < NN) s += fast_tanh(sa[nt][j] + bb) * qc;
        }
    }
#pragma unroll
    for (int off = 1; off < 64; off <<= 1) s += __shfl_xor(s, off);
    if (lane == 0) atomicAdd(&score[m], s);
}

// ================= beta =================
__global__ void k_beta(const float* __restrict__ score, float* __restrict__ beta_ws,
                       float* __restrict__ out) {
    if (threadIdx.x == 0) {
        float s0 = score[0] / (float)NN, s1 = score[1] / (float)NN, s2 = score[2] / (float)NN;
        float mx = fmaxf(s0, fmaxf(s1, s2));
        float e0 = expf(s0 - mx), e1 = expf(s1 - mx), e2 = expf(s2 - mx);
        float inv = 1.f / (e0 + e1 + e2);
        beta_ws[0] = e0 * inv; beta_ws[1] = e1 * inv; beta_ws[2] = e2 * inv;
        out[800000] = e0 * inv; out[800001] = e1 * inv; out[800002] = e2 * inv;
    }
}

// ================= output =================
__global__ __launch_bounds__(256) void k_out(const float* __restrict__ z,
                                             const float* __restrict__ beta,
                                             const float* __restrict__ Wo,
                                             const float* __restrict__ bo,
                                             float* __restrict__ out) {
    __shared__ float Zt[64 * 68];
    __shared__ float Wl[64 * 16];
    __shared__ float bl[16];
    const int tid = threadIdx.x, nbase = blockIdx.x * 64;
    float b0 = beta[0], b1 = beta[1], b2 = beta[2];
    for (int qq = tid; qq < 64 * 16; qq += 256) {
        int node = qq >> 4, k4 = qq & 15;
        int ng = nbase + node;
        float4 v = make_float4(0.f, 0.f, 0.f, 0.f);
        if (ng < NN) {
            float4 z0 = *(const float4*)&z[((size_t)0 * NN + ng) * 64 + k4 * 4];
            float4 z1 = *(const float4*)&z[((size_t)1 * NN + ng) * 64 + k4 * 4];
            float4 z2 = *(const float4*)&z[((size_t)2 * NN + ng) * 64 + k4 * 4];
            v.x = b0 * z0.x + b1 * z1.x + b2 * z2.x;
            v.y = b0 * z0.y + b1 * z1.y + b2 * z2.y;
            v.z = b0 * z0.z + b1 * z1.z + b2 * z2.z;
            v.w = b0 * z0.w + b1 * z1.w + b2 * z2.w;
        }
        *(float4*)&Zt[node * 68 + k4 * 4] = v;
    }
    for (int qq = tid; qq < 64 * 16 / 4; qq += 256)
        ((float4*)Wl)[qq] = ((const float4*)Wo)[qq];
    if (tid < 16) bl[tid] = bo[tid];
    __syncthreads();

    const int node = tid >> 2, cg = tid & 3;
    float4 a = make_float4(bl[cg * 4 + 0], bl[cg * 4 + 1], bl[cg * 4 + 2], bl[cg * 4 + 3]);
    for (int k = 0; k < 64; k++) {
        float zv = Zt[node * 68 + k];
        float4 w = *(const float4*)&Wl[k * 16 + cg * 4];
        a.x = fmaf(zv, w.x, a.x);
        a.y = fmaf(zv, w.y, a.y);
        a.z = fmaf(zv, w.z, a.z);
        a.w = fmaf(zv, w.w, a.w);
    }
    float mx = fmaxf(fmaxf(a.x, a.y), fmaxf(a.z, a.w));
    mx = fmaxf(mx, __shfl_xor(mx, 1));
    mx = fmaxf(mx, __shfl_xor(mx, 2));
    float sm = expf(a.x - mx) + expf(a.y - mx) + expf(a.z - mx) + expf(a.w - mx);
    sm += __shfl_xor(sm, 1);
    sm += __shfl_xor(sm, 2);
    float lse = mx + logf(sm);
    int ng = nbase + node;
    if (ng < NN) {
        float4 r = make_float4(a.x - lse, a.y - lse, a.z - lse, a.w - lse);
        *(float4*)&out[(size_t)ng * 16 + cg * 4] = r;
    }
}

extern "C" void kernel_launch(void* const* d_in, const int* in_sizes, int n_in,
                              void* d_out, int out_size, void* d_ws, size_t ws_size,
                              hipStream_t stream) {
    const float* x      = (const float*)d_in[0];
    const int*   ei     = (const int*)d_in[1];
    const float* W_enc  = (const float*)d_in[2];
    const float* b_enc  = (const float*)d_in[3];
    const float* W_conv = (const float*)d_in[4];
    const float* b_conv = (const float*)d_in[5];
    const float* W_dec  = (const float*)d_in[6];
    const float* b_dec  = (const float*)d_in[7];
    const float* W_s    = (const float*)d_in[8];
    const float* b_s    = (const float*)d_in[9];
    const float* qv     = (const float*)d_in[10];
    const float* W_o    = (const float*)d_in[11];
    const float* b_o    = (const float*)d_in[12];
    float* out = (float*)d_out;

    char* ws = (char*)d_ws;
    size_t off = 0;
    auto alloc = [&](size_t bytes) -> char* {
        char* p = ws + off;
        off = (off + bytes + 255) & ~(size_t)255;
        return p;
    };
    int*   row_ofs = (int*)alloc((size_t)MM * (NN + 1) * 4);
    float* rs      = (float*)alloc((size_t)MM * NN * 4);
    int*   sorted  = (int*)alloc((size_t)MM * EE * 4);
    u64*   queues  = (u64*)alloc((size_t)MM * NPART * QCAP * 8);
    int*   gcur    = (int*)alloc((size_t)MM * NPART * 4);
    int*   pbase   = (int*)alloc((size_t)MM * NPART * 4);
    float* score   = (float*)alloc(64);
    float* beta_ws = (float*)alloc(64);
    u16*   wbe     = (u16*)alloc((size_t)MM * 2048 * 8 * 2);
    u16*   wbc     = (u16*)alloc((size_t)MM * 1024 * 8 * 2);
    u16*   wbd     = (u16*)alloc((size_t)MM * 512 * 8 * 2);
    u16*   wbs     = (u16*)alloc((size_t)1024 * 8 * 2);
    u16*   xw_buf  = (u16*)alloc((size_t)NN * 128 * 2);
    u16*   gg_buf  = (u16*)alloc((size_t)NN * 128 * 2);
    float* z_buf   = (float*)alloc((size_t)MM * NN * 64 * 4);

    hipMemsetAsync(gcur, 0, (size_t)MM * NPART * 4, stream);
    hipMemsetAsync(score, 0, 16, stream);

    dim3 gbkt(BBLK, MM);
    dim3 gcsr(NPART * CSUB, MM);
    k_bucket<<<gbkt, 256, 0, stream>>>(ei, queues, gcur);
    k_pscan<<<1, 64, 0, stream>>>(gcur, pbase);
    k_csr<<<gcsr, 512, 0, stream>>>(queues, gcur, pbase, row_ofs, rs, sorted);
    k_prep<<<46, 256, 0, stream>>>(W_enc, W_conv, W_dec, W_s, wbe, wbc, wbd, wbs);

    const int GB = (NN + 63) / 64;   // 782
    for (int m = 0; m < MM; m++) {
        k_encconv<<<GB, 256, 0, stream>>>(x, wbe + (size_t)m * 2048 * 8,
                                          b_enc + (size_t)m * 2 * 64,
                                          wbc + (size_t)m * 1024 * 8, xw_buf);
        k_gather<<<(NN + 3) / 4, 256, 0, stream>>>(sorted + (size_t)m * EE,
                                                   row_ofs + (size_t)m * (NN + 1),
                                                   rs + (size_t)m * NN, xw_buf, gg_buf);
        k_post<<<GB, 256, 0, stream>>>(gg_buf, xw_buf, rs + (size_t)m * NN,
                                       b_conv + (size_t)m * 2 * 64,
                                       wbd + (size_t)m * 512 * 8,
                                       b_dec + (size_t)m * 2 * 32,
                                       wbs, b_s, qv,
                                       z_buf + (size_t)m * NN * 64, score, m);
    }
    k_beta<<<1, 64, 0, stream>>>(score, beta_ws, out);
    k_out<<<GB, 256, 0, stream>>>(z_buf, beta_ws, W_o, b_o, out);
}

// Round 8
// 466.586 us; speedup vs baseline: 1.4669x; 1.2519x over previous
//
#include <hip/hip_runtime.h>

#define NN 50000
#define EE 800000
#define MM 3
#define HH 2
#define IND 128
#define HIDD 64
#define HEADD 32
#define OUTD 16
#define ATTD 128

#define NBKT 64            // fine dst-buckets per metapath
#define BSZ 782            // dsts per bucket (64*782 = 50048 >= NN)

#define NG4 200000         // EE/4 int4 groups per metapath
#define BBLK 196           // bucket blocks per metapath
#define QCAP 13200         // queue capacity per (m,bucket); E[len]=12.5k, sigma~111

typedef unsigned short u16;
typedef unsigned long long u64;
typedef short bf16x8 __attribute__((ext_vector_type(8)));
typedef unsigned short u16x8 __attribute__((ext_vector_type(8)));
typedef u64 u64x2 __attribute__((ext_vector_type(2)));
typedef float f32x4 __attribute__((ext_vector_type(4)));

__device__ __forceinline__ float lrelu(float v) { return v > 0.f ? v : 0.1f * v; }

__device__ __forceinline__ float fast_tanh(float x) {
    float ax = fabsf(x);
    float e = __expf(-2.0f * ax);
    float t = (1.0f - e) * __builtin_amdgcn_rcpf(1.0f + e);
    return copysignf(t, x);
}

__device__ __forceinline__ u16 f2b(float f) {          // fp32 -> bf16 RNE
    union { float f; unsigned int u; } v; v.f = f;
    unsigned int r = v.u + 0x7fffu + ((v.u >> 16) & 1u);
    return (u16)(r >> 16);
}
__device__ __forceinline__ float b2f(u16 u) {
    union { unsigned int u; float f; } v; v.u = ((unsigned int)u) << 16; return v.f;
}

// ================= phase A: bucket edges into 64 fine dst-buckets =================
// 4096 edges/block over 64 buckets -> ~512 B contiguous per bucket per block: coalesced.
__global__ __launch_bounds__(256) void k_bucket(const int* __restrict__ ei,
                                                u64* __restrict__ queues,
                                                int* __restrict__ gcur) {
    __shared__ int cnt[NBKT];
    __shared__ int base[NBKT];
    const int m = blockIdx.y, tid = threadIdx.x;
    const int4* s4 = (const int4*)(ei + (size_t)m * 2 * EE);
    const int4* d4 = (const int4*)(ei + (size_t)m * 2 * EE + EE);
    const int q0 = blockIdx.x * 1024;
    if (tid < NBKT) cnt[tid] = 0;
    __syncthreads();
#pragma unroll
    for (int i = 0; i < 4; i++) {
        int q = q0 + i * 256 + tid;
        if (q < NG4) {
            int4 dv = d4[q];
            atomicAdd(&cnt[dv.x / BSZ], 1);
            atomicAdd(&cnt[dv.y / BSZ], 1);
            atomicAdd(&cnt[dv.z / BSZ], 1);
            atomicAdd(&cnt[dv.w / BSZ], 1);
        }
    }
    __syncthreads();
    if (tid < NBKT) { base[tid] = atomicAdd(&gcur[m * NBKT + tid], cnt[tid]); cnt[tid] = 0; }
    __syncthreads();
#pragma unroll
    for (int i = 0; i < 4; i++) {
        int q = q0 + i * 256 + tid;
        if (q < NG4) {
            int4 dv = d4[q];
            int4 sv = s4[q];
            int ds[4] = {dv.x, dv.y, dv.z, dv.w};
            int ss[4] = {sv.x, sv.y, sv.z, sv.w};
#pragma unroll
            for (int e = 0; e < 4; e++) {
                int b = ds[e] / BSZ;
                int slot = base[b] + atomicAdd(&cnt[b], 1);
                if (slot < QCAP) {
                    u64 pk = ((u64)(unsigned)ds[e] << 32) | (unsigned)ss[e];
                    queues[((size_t)(m * NBKT + b)) * QCAP + slot] = pk;
                }
            }
        }
    }
}

// ================= bucket-base scan (3 x 64 values) =================
__global__ void k_pscan(const int* __restrict__ gcur, int* __restrict__ pbase) {
    int t = threadIdx.x;
    if (t < MM) {
        int run = 0;
        for (int b = 0; b < NBKT; b++) {
            int L = gcur[t * NBKT + b]; if (L > QCAP) L = QCAP;
            pbase[t * NBKT + b] = run; run += L;
        }
    }
}

// ================= CSR build: one block owns one (m, bucket) =================
// Reads ONLY its own ~12.5k-edge queue (16B vector loads; pass 2 is L2-warm).
// All srt writes for the bucket's CSR window come from this one block within
// a few microseconds -> lines fill before writeback (keeps R7's write fix).
__global__ __launch_bounds__(512) void k_csr(const u64* __restrict__ queues,
                                             const int* __restrict__ gcur,
                                             const int* __restrict__ pbase,
                                             int* __restrict__ ofs,
                                             float* __restrict__ rs,
                                             int* __restrict__ sorted) {
    __shared__ int cnt[BSZ];
    __shared__ int wscan[8];
    const int m = blockIdx.y;
    const int b = blockIdx.x;
    const int tid = threadIdx.x;
    const int lane = tid & 63, w = tid >> 6;
    int qlen = gcur[m * NBKT + b]; if (qlen > QCAP) qlen = QCAP;
    const u64* q = queues + ((size_t)(m * NBKT + b)) * QCAP;
    const u64x2* q2 = (const u64x2*)q;
    const int dlo = b * BSZ;
    const int nd = min(dlo + BSZ, NN) - dlo;
    const int n2 = qlen >> 1;
    for (int i = tid; i < BSZ; i += 512) cnt[i] = 0;
    __syncthreads();
    // pass 1: count own bucket
    for (int i = tid; i < n2; i += 512) {
        u64x2 e = q2[i];
        atomicAdd(&cnt[(int)(e.x >> 32) - dlo], 1);
        atomicAdd(&cnt[(int)(e.y >> 32) - dlo], 1);
    }
    if (tid == 0 && (qlen & 1))
        atomicAdd(&cnt[(int)(q[qlen - 1] >> 32) - dlo], 1);
    __syncthreads();
    // exclusive scan of cnt (2 elems/thread)
    const int c0 = tid * 2;
    int v0 = (c0 < BSZ) ? cnt[c0] : 0;
    int v1 = (c0 + 1 < BSZ) ? cnt[c0 + 1] : 0;
    int s = v0 + v1;
    int vv = s;
    for (int off = 1; off < 64; off <<= 1) { int t = __shfl_up(vv, off); if (lane >= off) vv += t; }
    if (lane == 63) wscan[w] = vv;
    __syncthreads();
    if (tid == 0) { int run = 0; for (int j = 0; j < 8; j++) { int t = wscan[j]; wscan[j] = run; run += t; } }
    __syncthreads();
    int excl = wscan[w] + vv - s;
    int g0 = pbase[m * NBKT + b] + excl;
    int g1 = g0 + v0;
    if (c0 < nd) {
        ofs[(size_t)m * (NN + 1) + dlo + c0] = g0;
        rs[(size_t)m * NN + dlo + c0] = rsqrtf((float)(v0 + 1));
    }
    if (c0 + 1 < nd) {
        ofs[(size_t)m * (NN + 1) + dlo + c0 + 1] = g1;
        rs[(size_t)m * NN + dlo + c0 + 1] = rsqrtf((float)(v1 + 1));
    }
    if (b == NBKT - 1 && tid == 0)
        ofs[(size_t)m * (NN + 1) + NN] = EE;
    __syncthreads();
    if (c0 < BSZ) cnt[c0] = g0;
    if (c0 + 1 < BSZ) cnt[c0 + 1] = g1;
    __syncthreads();
    // pass 2: scatter via LDS cursors (queue L2-warm from pass 1)
    int* srt = sorted + (size_t)m * EE;
    for (int i = tid; i < n2; i += 512) {
        u64x2 e = q2[i];
        int p0 = atomicAdd(&cnt[(int)(e.x >> 32) - dlo], 1);
        srt[p0] = (int)(e.x & 0xffffffffu);
        int p1 = atomicAdd(&cnt[(int)(e.y >> 32) - dlo], 1);
        srt[p1] = (int)(e.y & 0xffffffffu);
    }
    if (tid == 0 && (qlen & 1)) {
        u64 e = q[qlen - 1];
        int p0 = atomicAdd(&cnt[(int)(e >> 32) - dlo], 1);
        srt[p0] = (int)(e & 0xffffffffu);
    }
}

// ================= weight prep: fp32 -> bf16 MFMA B-fragment layout =================
__global__ __launch_bounds__(256) void k_prep(const float* __restrict__ We, const float* __restrict__ Wc,
                                              const float* __restrict__ Wd, const float* __restrict__ Ws,
                                              u16* __restrict__ wbe, u16* __restrict__ wbc,
                                              u16* __restrict__ wbd, u16* __restrict__ wbs) {
    int t = blockIdx.x * 256 + threadIdx.x;
    if (t >= 11776) return;
    bf16x8 val;
    u16* dst;
    if (t < 6144) {                       // enc: per m, 8 nt x 4 ks x 64 lanes, K=128, N=128
        int m = t >> 11, r = t & 2047;
        int nt = r >> 8, ks = (r >> 6) & 3, lane = r & 63;
        int n = nt * 16 + (lane & 15), h = n >> 6, o = n & 63;
        int kb = ks * 32 + (lane >> 4) * 8;
        const float* w = We + ((size_t)(m * 2 + h) * 128) * 64;
#pragma unroll
        for (int j = 0; j < 8; j++) val[j] = (short)f2b(w[(size_t)(kb + j) * 64 + o]);
        dst = wbe + ((size_t)m * 2048 + r) * 8;
    } else if (t < 9216) {                // conv: per m, 8 nt x 2 ks, K=64, N=128 (head-blockdiag)
        int u = t - 6144;
        int m = u >> 10, r = u & 1023;
        int nt = r >> 7, ks = (r >> 6) & 1, lane = r & 63;
        int h = nt >> 2, o = (nt & 3) * 16 + (lane & 15);
        int kb = ks * 32 + (lane >> 4) * 8;
        const float* w = Wc + ((size_t)(m * 2 + h) * 64) * 64;
#pragma unroll
        for (int j = 0; j < 8; j++) val[j] = (short)f2b(w[(size_t)(kb + j) * 64 + o]);
        dst = wbc + ((size_t)m * 1024 + r) * 8;
    } else if (t < 10752) {               // dec: per m, 4 nt x 2 ks, K=64, N=64 (head-blockdiag)
        int u = t - 9216;
        int m = u >> 9, r = u & 511;
        int nt = r >> 7, ks = (r >> 6) & 1, lane = r & 63;
        int h = nt >> 1, o = (nt & 1) * 16 + (lane & 15);
        int kb = ks * 32 + (lane >> 4) * 8;
        const float* w = Wd + ((size_t)(m * 2 + h) * 64) * 32;
#pragma unroll
        for (int j = 0; j < 8; j++) val[j] = (short)f2b(w[(size_t)(kb + j) * 32 + o]);
        dst = wbd + ((size_t)m * 512 + r) * 8;
    } else {                              // W_s: 8 nt x 2 ks, K=64, N=128
        int r = t - 10752;
        int nt = r >> 7, ks = (r >> 6) & 1, lane = r & 63;
        int n = nt * 16 + (lane & 15);
        int kb = ks * 32 + (lane >> 4) * 8;
#pragma unroll
        for (int j = 0; j < 8; j++) val[j] = (short)f2b(Ws[(size_t)(kb + j) * 128 + n]);
        dst = wbs + (size_t)r * 8;
    }
    *(bf16x8*)dst = val;
}

// ================= fused enc+conv: xw = (lrelu(x@We+be)) @ Wc, h tile via LDS =================
#define HLS 133   // fp32 row stride: 5*r mod 32 -> 2 lanes/bank (free)
__global__ __launch_bounds__(256) void k_encconv(const float* __restrict__ x,
                                                 const u16* __restrict__ wbe,
                                                 const float* __restrict__ be,
                                                 const u16* __restrict__ wbc,
                                                 u16* __restrict__ xw) {
    __shared__ float hl[64 * HLS];
    const int tid = threadIdx.x, lane = tid & 63, wave = tid >> 6;
    const int quad = lane >> 4, c16 = lane & 15;
    const int row = blockIdx.x * 64 + wave * 16 + c16;
    const bool ok = row < NN;
    const bf16x8* wbE = (const bf16x8*)wbe;
    f32x4 zero = {0.f, 0.f, 0.f, 0.f};
    f32x4 acc[8];
#pragma unroll
    for (int nt = 0; nt < 8; nt++) acc[nt] = zero;
#pragma unroll
    for (int ks = 0; ks < 4; ks++) {
        bf16x8 a = {0, 0, 0, 0, 0, 0, 0, 0};
        if (ok) {
            const float* xp = x + (size_t)row * 128 + ks * 32 + quad * 8;
            float4 xa = *(const float4*)xp;
            float4 xb = *(const float4*)(xp + 4);
            a[0] = (short)f2b(xa.x); a[1] = (short)f2b(xa.y);
            a[2] = (short)f2b(xa.z); a[3] = (short)f2b(xa.w);
            a[4] = (short)f2b(xb.x); a[5] = (short)f2b(xb.y);
            a[6] = (short)f2b(xb.z); a[7] = (short)f2b(xb.w);
        }
#pragma unroll
        for (int nt = 0; nt < 8; nt++)
            acc[nt] = __builtin_amdgcn_mfma_f32_16x16x32_bf16(a, wbE[(nt * 4 + ks) * 64 + lane], acc[nt], 0, 0, 0);
    }
    const int rbl = wave * 16 + quad * 4;
#pragma unroll
    for (int nt = 0; nt < 8; nt++) {
        int col = nt * 16 + c16, hh = col >> 6, o = col & 63;
        float bias = be[hh * 64 + o];
#pragma unroll
        for (int j = 0; j < 4; j++) {
            int rl = rbl + j;
            int rg = blockIdx.x * 64 + rl;
            hl[rl * HLS + col] = (rg < NN) ? lrelu(acc[nt][j] + bias) : 0.f;
        }
    }
    __syncthreads();
    const bf16x8* wbC = (const bf16x8*)wbc;
    f32x4 cacc[8];
#pragma unroll
    for (int nt = 0; nt < 8; nt++) cacc[nt] = zero;
    const int rl = wave * 16 + c16;
#pragma unroll
    for (int ks = 0; ks < 2; ks++) {
        bf16x8 a0, a1;
        const float* hp = &hl[rl * HLS + ks * 32 + quad * 8];
#pragma unroll
        for (int j = 0; j < 8; j++) { a0[j] = (short)f2b(hp[j]); a1[j] = (short)f2b(hp[64 + j]); }
#pragma unroll
        for (int nt = 0; nt < 8; nt++)
            cacc[nt] = __builtin_amdgcn_mfma_f32_16x16x32_bf16(nt < 4 ? a0 : a1, wbC[(nt * 2 + ks) * 64 + lane], cacc[nt], 0, 0, 0);
    }
#pragma unroll
    for (int nt = 0; nt < 8; nt++) {
        int col = nt * 16 + c16;
#pragma unroll
        for (int j = 0; j < 4; j++) {
            int r = blockIdx.x * 64 + rbl + j;
            if (r < NN) xw[(size_t)r * 128 + col] = f2b(cacc[nt][j]);
        }
    }
}

// ================= gather: gg[dst] = rs[dst] * sum_src rs[src]*xw[src] =================
__global__ __launch_bounds__(256) void k_gather(const int* __restrict__ sorted,
                                                const int* __restrict__ ofs,
                                                const float* __restrict__ rs,
                                                const u16* __restrict__ xw,
                                                u16* __restrict__ gg) {
    const int tid = threadIdx.x;
    const int dst = blockIdx.x * 4 + (tid >> 6);
    if (dst >= NN) return;
    const int lane = tid & 63, p = lane >> 4, c = lane & 15;
    int beg = ofs[dst], end = ofs[dst + 1];
    float acc[8] = {0.f, 0.f, 0.f, 0.f, 0.f, 0.f, 0.f, 0.f};
    for (int j = beg + p; j < end; j += 4) {
        int s = sorted[j];
        float cf = rs[s];
        u16x8 v = *(const u16x8*)&xw[(size_t)s * 128 + c * 8];
#pragma unroll
        for (int k = 0; k < 8; k++) acc[k] = fmaf(cf, b2f(v[k]), acc[k]);
    }
#pragma unroll
    for (int k = 0; k < 8; k++) {
        acc[k] += __shfl_down(acc[k], 16);
        acc[k] += __shfl_down(acc[k], 32);
    }
    if (p == 0) {
        float rsd = rs[dst];
        u16x8 o;
#pragma unroll
        for (int k = 0; k < 8; k++) o[k] = f2b(acc[k] * rsd);
        *(u16x8*)&gg[(size_t)dst * 128 + c * 8] = o;
    }
}

// ================= post+score =================
__global__ __launch_bounds__(256) void k_post(const u16* __restrict__ gg,
                                              const u16* __restrict__ xw,
                                              const float* __restrict__ rs,
                                              const float* __restrict__ bconv,
                                              const u16* __restrict__ wbd,
                                              const float* __restrict__ bdec,
                                              const u16* __restrict__ wbs,
                                              const float* __restrict__ bs,
                                              const float* __restrict__ qv,
                                              float* __restrict__ z,
                                              float* __restrict__ score, int m) {
    __shared__ float zl[64 * 68];
    const int tid = threadIdx.x, lane = tid & 63, wave = tid >> 6;
    const int quad = lane >> 4, c16 = lane & 15;
    const int row = blockIdx.x * 64 + wave * 16 + c16;
    const bool ok = row < NN;
    float rs2 = 0.f;
    if (ok) { float t = rs[row]; rs2 = t * t; }
    const bf16x8* wd = (const bf16x8*)wbd;
    f32x4 acc[4];
    f32x4 zero = {0.f, 0.f, 0.f, 0.f};
#pragma unroll
    for (int nt = 0; nt < 4; nt++) acc[nt] = zero;
#pragma unroll
    for (int ks = 0; ks < 2; ks++) {
        bf16x8 a0 = {0,0,0,0,0,0,0,0}, a1 = {0,0,0,0,0,0,0,0};
        if (ok) {
            int k0 = ks * 32 + quad * 8;
            const u16* gp0 = &gg[(size_t)row * 128 + k0];
            const u16* xp0 = &xw[(size_t)row * 128 + k0];
            const u16* gp1 = gp0 + 64;
            const u16* xp1 = xp0 + 64;
#pragma unroll
            for (int j = 0; j < 8; j++) {
                float v0 = lrelu(fmaf(b2f(xp0[j]), rs2, b2f(gp0[j])) + bconv[k0 + j]);
                float v1 = lrelu(fmaf(b2f(xp1[j]), rs2, b2f(gp1[j])) + bconv[64 + k0 + j]);
                a0[j] = (short)f2b(v0);
                a1[j] = (short)f2b(v1);
            }
        }
#pragma unroll
        for (int nt = 0; nt < 4; nt++)
            acc[nt] = __builtin_amdgcn_mfma_f32_16x16x32_bf16(nt < 2 ? a0 : a1, wd[(nt * 2 + ks) * 64 + lane], acc[nt], 0, 0, 0);
    }
    const int rbl = wave * 16 + quad * 4;
#pragma unroll
    for (int nt = 0; nt < 4; nt++) {
        int col = nt * 16 + c16, hh = col >> 5, o = col & 31;
        float bias = bdec[hh * 32 + o];
#pragma unroll
        for (int j = 0; j < 4; j++) {
            int rl = rbl + j;
            int rg = blockIdx.x * 64 + rl;
            zl[rl * 68 + col] = (rg < NN) ? (acc[nt][j] + bias) : 0.f;
        }
    }
    __syncthreads();
    {
        int rl = tid >> 2, cq = tid & 3;
        int rg = blockIdx.x * 64 + rl;
        if (rg < NN) {
#pragma unroll
            for (int i = 0; i < 4; i++) {
                int c4 = (cq * 4 + i) * 4;
                *(float4*)&z[(size_t)rg * 64 + c4] = *(const float4*)&zl[rl * 68 + c4];
            }
        }
    }
    const bf16x8* wsb = (const bf16x8*)wbs;
    f32x4 sa[8];
#pragma unroll
    for (int nt = 0; nt < 8; nt++) sa[nt] = zero;
#pragma unroll
    for (int ks = 0; ks < 2; ks++) {
        bf16x8 a;
        const float* zp = &zl[(wave * 16 + c16) * 68 + ks * 32 + quad * 8];
#pragma unroll
        for (int j = 0; j < 8; j++) a[j] = (short)f2b(zp[j]);
#pragma unroll
        for (int nt = 0; nt < 8; nt++)
            sa[nt] = __builtin_amdgcn_mfma_f32_16x16x32_bf16(a, wsb[(nt * 2 + ks) * 64 + lane], sa[nt], 0, 0, 0);
    }
    float s = 0.f;
#pragma unroll
    for (int nt = 0; nt < 8; nt++) {
        int col = nt * 16 + c16;
        float qc = qv[col], bb = bs[col];
#pragma unroll
        for (int j = 0; j < 4; j++) {
            int rg = blockIdx.x * 64 + rbl + j;
            if (rg < NN) s += fast_tanh(sa[nt][j] + bb) * qc;
        }
    }
#pragma unroll
    for (int off = 1; off < 64; off <<= 1) s += __shfl_xor(s, off);
    if (lane == 0) atomicAdd(&score[m], s);
}

// ================= beta =================
__global__ void k_beta(const float* __restrict__ score, float* __restrict__ beta_ws,
                       float* __restrict__ out) {
    if (threadIdx.x == 0) {
        float s0 = score[0] / (float)NN, s1 = score[1] / (float)NN, s2 = score[2] / (float)NN;
        float mx = fmaxf(s0, fmaxf(s1, s2));
        float e0 = expf(s0 - mx), e1 = expf(s1 - mx), e2 = expf(s2 - mx);
        float inv = 1.f / (e0 + e1 + e2);
        beta_ws[0] = e0 * inv; beta_ws[1] = e1 * inv; beta_ws[2] = e2 * inv;
        out[800000] = e0 * inv; out[800001] = e1 * inv; out[800002] = e2 * inv;
    }
}

// ================= output =================
__global__ __launch_bounds__(256) void k_out(const float* __restrict__ z,
                                             const float* __restrict__ beta,
                                             const float* __restrict__ Wo,
                                             const float* __restrict__ bo,
                                             float* __restrict__ out) {
    __shared__ float Zt[64 * 68];
    __shared__ float Wl[64 * 16];
    __shared__ float bl[16];
    const int tid = threadIdx.x, nbase = blockIdx.x * 64;
    float b0 = beta[0], b1 = beta[1], b2 = beta[2];
    for (int qq = tid; qq < 64 * 16; qq += 256) {
        int node = qq >> 4, k4 = qq & 15;
        int ng = nbase + node;
        float4 v = make_float4(0.f, 0.f, 0.f, 0.f);
        if (ng < NN) {
            float4 z0 = *(const float4*)&z[((size_t)0 * NN + ng) * 64 + k4 * 4];
            float4 z1 = *(const float4*)&z[((size_t)1 * NN + ng) * 64 + k4 * 4];
            float4 z2 = *(const float4*)&z[((size_t)2 * NN + ng) * 64 + k4 * 4];
            v.x = b0 * z0.x + b1 * z1.x + b2 * z2.x;
            v.y = b0 * z0.y + b1 * z1.y + b2 * z2.y;
            v.z = b0 * z0.z + b1 * z1.z + b2 * z2.z;
            v.w = b0 * z0.w + b1 * z1.w + b2 * z2.w;
        }
        *(float4*)&Zt[node * 68 + k4 * 4] = v;
    }
    for (int qq = tid; qq < 64 * 16 / 4; qq += 256)
        ((float4*)Wl)[qq] = ((const float4*)Wo)[qq];
    if (tid < 16) bl[tid] = bo[tid];
    __syncthreads();

    const int node = tid >> 2, cg = tid & 3;
    float4 a = make_float4(bl[cg * 4 + 0], bl[cg * 4 + 1], bl[cg * 4 + 2], bl[cg * 4 + 3]);
    for (int k = 0; k < 64; k++) {
        float zv = Zt[node * 68 + k];
        float4 w = *(const float4*)&Wl[k * 16 + cg * 4];
        a.x = fmaf(zv, w.x, a.x);
        a.y = fmaf(zv, w.y, a.y);
        a.z = fmaf(zv, w.z, a.z);
        a.w = fmaf(zv, w.w, a.w);
    }
    float mx = fmaxf(fmaxf(a.x, a.y), fmaxf(a.z, a.w));
    mx = fmaxf(mx, __shfl_xor(mx, 1));
    mx = fmaxf(mx, __shfl_xor(mx, 2));
    float sm = expf(a.x - mx) + expf(a.y - mx) + expf(a.z - mx) + expf(a.w - mx);
    sm += __shfl_xor(sm, 1);
    sm += __shfl_xor(sm, 2);
    float lse = mx + logf(sm);
    int ng = nbase + node;
    if (ng < NN) {
        float4 r = make_float4(a.x - lse, a.y - lse, a.z - lse, a.w - lse);
        *(float4*)&out[(size_t)ng * 16 + cg * 4] = r;
    }
}

extern "C" void kernel_launch(void* const* d_in, const int* in_sizes, int n_in,
                              void* d_out, int out_size, void* d_ws, size_t ws_size,
                              hipStream_t stream) {
    const float* x      = (const float*)d_in[0];
    const int*   ei     = (const int*)d_in[1];
    const float* W_enc  = (const float*)d_in[2];
    const float* b_enc  = (const float*)d_in[3];
    const float* W_conv = (const float*)d_in[4];
    const float* b_conv = (const float*)d_in[5];
    const float* W_dec  = (const float*)d_in[6];
    const float* b_dec  = (const float*)d_in[7];
    const float* W_s    = (const float*)d_in[8];
    const float* b_s    = (const float*)d_in[9];
    const float* qv     = (const float*)d_in[10];
    const float* W_o    = (const float*)d_in[11];
    const float* b_o    = (const float*)d_in[12];
    float* out = (float*)d_out;

    char* ws = (char*)d_ws;
    size_t off = 0;
    auto alloc = [&](size_t bytes) -> char* {
        char* p = ws + off;
        off = (off + bytes + 255) & ~(size_t)255;
        return p;
    };
    int*   row_ofs = (int*)alloc((size_t)MM * (NN + 1) * 4);
    float* rs      = (float*)alloc((size_t)MM * NN * 4);
    int*   sorted  = (int*)alloc((size_t)MM * EE * 4);
    u64*   queues  = (u64*)alloc((size_t)MM * NBKT * QCAP * 8);
    int*   gcur    = (int*)alloc((size_t)MM * NBKT * 4);
    int*   pbase   = (int*)alloc((size_t)MM * NBKT * 4);
    float* score   = (float*)alloc(64);
    float* beta_ws = (float*)alloc(64);
    u16*   wbe     = (u16*)alloc((size_t)MM * 2048 * 8 * 2);
    u16*   wbc     = (u16*)alloc((size_t)MM * 1024 * 8 * 2);
    u16*   wbd     = (u16*)alloc((size_t)MM * 512 * 8 * 2);
    u16*   wbs     = (u16*)alloc((size_t)1024 * 8 * 2);
    u16*   xw_buf  = (u16*)alloc((size_t)NN * 128 * 2);
    u16*   gg_buf  = (u16*)alloc((size_t)NN * 128 * 2);
    float* z_buf   = (float*)alloc((size_t)MM * NN * 64 * 4);

    hipMemsetAsync(gcur, 0, (size_t)MM * NBKT * 4, stream);
    hipMemsetAsync(score, 0, 16, stream);

    dim3 gbkt(BBLK, MM);
    dim3 gcsr(NBKT, MM);
    k_bucket<<<gbkt, 256, 0, stream>>>(ei, queues, gcur);
    k_pscan<<<1, 64, 0, stream>>>(gcur, pbase);
    k_csr<<<gcsr, 512, 0, stream>>>(queues, gcur, pbase, row_ofs, rs, sorted);
    k_prep<<<46, 256, 0, stream>>>(W_enc, W_conv, W_dec, W_s, wbe, wbc, wbd, wbs);

    const int GB = (NN + 63) / 64;   // 782
    for (int m = 0; m < MM; m++) {
        k_encconv<<<GB, 256, 0, stream>>>(x, wbe + (size_t)m * 2048 * 8,
                                          b_enc + (size_t)m * 2 * 64,
                                          wbc + (size_t)m * 1024 * 8, xw_buf);
        k_gather<<<(NN + 3) / 4, 256, 0, stream>>>(sorted + (size_t)m * EE,
                                                   row_ofs + (size_t)m * (NN + 1),
                                                   rs + (size_t)m * NN, xw_buf, gg_buf);
        k_post<<<GB, 256, 0, stream>>>(gg_buf, xw_buf, rs + (size_t)m * NN,
                                       b_conv + (size_t)m * 2 * 64,
                                       wbd + (size_t)m * 512 * 8,
                                       b_dec + (size_t)m * 2 * 32,
                                       wbs, b_s, qv,
                                       z_buf + (size_t)m * NN * 64, score, m);
    }
    k_beta<<<1, 64, 0, stream>>>(score, beta_ws, out);
    k_out<<<GB, 256, 0, stream>>>(z_buf, beta_ws, W_o, b_o, out);
}

// Round 9
// 374.937 us; speedup vs baseline: 1.8255x; 1.2444x over previous
//
#include <hip/hip_runtime.h>

#define NN 50000
#define EE 800000
#define MM 3
#define HH 2
#define IND 128
#define HIDD 64
#define HEADD 32
#define OUTD 16
#define ATTD 128

#define NBKT 64            // fine dst-buckets per metapath
#define BSZ 782            // dsts per bucket (64*782 = 50048 >= NN)

#define NG4 200000         // EE/4 int4 groups per metapath
#define BBLK 196           // bucket blocks per metapath
#define QCAP 13200         // queue capacity per (m,bucket)

#define GLS 136            // ggl LDS row stride (u16): 16B aligned, conflict-spread

typedef unsigned short u16;
typedef unsigned long long u64;
typedef short bf16x8 __attribute__((ext_vector_type(8)));
typedef unsigned short u16x8 __attribute__((ext_vector_type(8)));
typedef u64 u64x2 __attribute__((ext_vector_type(2)));
typedef float f32x4 __attribute__((ext_vector_type(4)));

__device__ __forceinline__ float lrelu(float v) { return v > 0.f ? v : 0.1f * v; }

__device__ __forceinline__ float fast_tanh(float x) {
    float ax = fabsf(x);
    float e = __expf(-2.0f * ax);
    float t = (1.0f - e) * __builtin_amdgcn_rcpf(1.0f + e);
    return copysignf(t, x);
}

__device__ __forceinline__ u16 f2b(float f) {          // fp32 -> bf16 RNE
    union { float f; unsigned int u; } v; v.f = f;
    unsigned int r = v.u + 0x7fffu + ((v.u >> 16) & 1u);
    return (u16)(r >> 16);
}
__device__ __forceinline__ float b2f(u16 u) {
    union { unsigned int u; float f; } v; v.u = ((unsigned int)u) << 16; return v.f;
}

// ================= phase A: bucket edges into 64 fine dst-buckets =================
__global__ __launch_bounds__(256) void k_bucket(const int* __restrict__ ei,
                                                u64* __restrict__ queues,
                                                int* __restrict__ gcur) {
    __shared__ int cnt[NBKT];
    __shared__ int base[NBKT];
    const int m = blockIdx.y, tid = threadIdx.x;
    const int4* s4 = (const int4*)(ei + (size_t)m * 2 * EE);
    const int4* d4 = (const int4*)(ei + (size_t)m * 2 * EE + EE);
    const int q0 = blockIdx.x * 1024;
    if (tid < NBKT) cnt[tid] = 0;
    __syncthreads();
#pragma unroll
    for (int i = 0; i < 4; i++) {
        int q = q0 + i * 256 + tid;
        if (q < NG4) {
            int4 dv = d4[q];
            atomicAdd(&cnt[dv.x / BSZ], 1);
            atomicAdd(&cnt[dv.y / BSZ], 1);
            atomicAdd(&cnt[dv.z / BSZ], 1);
            atomicAdd(&cnt[dv.w / BSZ], 1);
        }
    }
    __syncthreads();
    if (tid < NBKT) { base[tid] = atomicAdd(&gcur[m * NBKT + tid], cnt[tid]); cnt[tid] = 0; }
    __syncthreads();
#pragma unroll
    for (int i = 0; i < 4; i++) {
        int q = q0 + i * 256 + tid;
        if (q < NG4) {
            int4 dv = d4[q];
            int4 sv = s4[q];
            int ds[4] = {dv.x, dv.y, dv.z, dv.w};
            int ss[4] = {sv.x, sv.y, sv.z, sv.w};
#pragma unroll
            for (int e = 0; e < 4; e++) {
                int b = ds[e] / BSZ;
                int slot = base[b] + atomicAdd(&cnt[b], 1);
                if (slot < QCAP) {
                    u64 pk = ((u64)(unsigned)ds[e] << 32) | (unsigned)ss[e];
                    queues[((size_t)(m * NBKT + b)) * QCAP + slot] = pk;
                }
            }
        }
    }
}

// ================= bucket-base scan (3 x 64 values) =================
__global__ void k_pscan(const int* __restrict__ gcur, int* __restrict__ pbase) {
    int t = threadIdx.x;
    if (t < MM) {
        int run = 0;
        for (int b = 0; b < NBKT; b++) {
            int L = gcur[t * NBKT + b]; if (L > QCAP) L = QCAP;
            pbase[t * NBKT + b] = run; run += L;
        }
    }
}

// ================= CSR build: one block owns one (m, bucket) =================
__global__ __launch_bounds__(512) void k_csr(const u64* __restrict__ queues,
                                             const int* __restrict__ gcur,
                                             const int* __restrict__ pbase,
                                             int* __restrict__ ofs,
                                             float* __restrict__ rs,
                                             int* __restrict__ sorted) {
    __shared__ int cnt[BSZ];
    __shared__ int wscan[8];
    const int m = blockIdx.y;
    const int b = blockIdx.x;
    const int tid = threadIdx.x;
    const int lane = tid & 63, w = tid >> 6;
    int qlen = gcur[m * NBKT + b]; if (qlen > QCAP) qlen = QCAP;
    const u64* q = queues + ((size_t)(m * NBKT + b)) * QCAP;
    const u64x2* q2 = (const u64x2*)q;
    const int dlo = b * BSZ;
    const int nd = min(dlo + BSZ, NN) - dlo;
    const int n2 = qlen >> 1;
    for (int i = tid; i < BSZ; i += 512) cnt[i] = 0;
    __syncthreads();
    for (int i = tid; i < n2; i += 512) {
        u64x2 e = q2[i];
        atomicAdd(&cnt[(int)(e.x >> 32) - dlo], 1);
        atomicAdd(&cnt[(int)(e.y >> 32) - dlo], 1);
    }
    if (tid == 0 && (qlen & 1))
        atomicAdd(&cnt[(int)(q[qlen - 1] >> 32) - dlo], 1);
    __syncthreads();
    const int c0 = tid * 2;
    int v0 = (c0 < BSZ) ? cnt[c0] : 0;
    int v1 = (c0 + 1 < BSZ) ? cnt[c0 + 1] : 0;
    int s = v0 + v1;
    int vv = s;
    for (int off = 1; off < 64; off <<= 1) { int t = __shfl_up(vv, off); if (lane >= off) vv += t; }
    if (lane == 63) wscan[w] = vv;
    __syncthreads();
    if (tid == 0) { int run = 0; for (int j = 0; j < 8; j++) { int t = wscan[j]; wscan[j] = run; run += t; } }
    __syncthreads();
    int excl = wscan[w] + vv - s;
    int g0 = pbase[m * NBKT + b] + excl;
    int g1 = g0 + v0;
    if (c0 < nd) {
        ofs[(size_t)m * (NN + 1) + dlo + c0] = g0;
        rs[(size_t)m * NN + dlo + c0] = rsqrtf((float)(v0 + 1));
    }
    if (c0 + 1 < nd) {
        ofs[(size_t)m * (NN + 1) + dlo + c0 + 1] = g1;
        rs[(size_t)m * NN + dlo + c0 + 1] = rsqrtf((float)(v1 + 1));
    }
    if (b == NBKT - 1 && tid == 0)
        ofs[(size_t)m * (NN + 1) + NN] = EE;
    __syncthreads();
    if (c0 < BSZ) cnt[c0] = g0;
    if (c0 + 1 < BSZ) cnt[c0 + 1] = g1;
    __syncthreads();
    int* srt = sorted + (size_t)m * EE;
    for (int i = tid; i < n2; i += 512) {
        u64x2 e = q2[i];
        int p0 = atomicAdd(&cnt[(int)(e.x >> 32) - dlo], 1);
        srt[p0] = (int)(e.x & 0xffffffffu);
        int p1 = atomicAdd(&cnt[(int)(e.y >> 32) - dlo], 1);
        srt[p1] = (int)(e.y & 0xffffffffu);
    }
    if (tid == 0 && (qlen & 1)) {
        u64 e = q[qlen - 1];
        int p0 = atomicAdd(&cnt[(int)(e >> 32) - dlo], 1);
        srt[p0] = (int)(e & 0xffffffffu);
    }
}

// ================= weight prep: fp32 -> bf16 MFMA B-fragment layout =================
__global__ __launch_bounds__(256) void k_prep(const float* __restrict__ We, const float* __restrict__ Wc,
                                              const float* __restrict__ Wd, const float* __restrict__ Ws,
                                              u16* __restrict__ wbe, u16* __restrict__ wbc,
                                              u16* __restrict__ wbd, u16* __restrict__ wbs) {
    int t = blockIdx.x * 256 + threadIdx.x;
    if (t >= 11776) return;
    bf16x8 val;
    u16* dst;
    if (t < 6144) {                       // enc
        int m = t >> 11, r = t & 2047;
        int nt = r >> 8, ks = (r >> 6) & 3, lane = r & 63;
        int n = nt * 16 + (lane & 15), h = n >> 6, o = n & 63;
        int kb = ks * 32 + (lane >> 4) * 8;
        const float* w = We + ((size_t)(m * 2 + h) * 128) * 64;
#pragma unroll
        for (int j = 0; j < 8; j++) val[j] = (short)f2b(w[(size_t)(kb + j) * 64 + o]);
        dst = wbe + ((size_t)m * 2048 + r) * 8;
    } else if (t < 9216) {                // conv
        int u = t - 6144;
        int m = u >> 10, r = u & 1023;
        int nt = r >> 7, ks = (r >> 6) & 1, lane = r & 63;
        int h = nt >> 2, o = (nt & 3) * 16 + (lane & 15);
        int kb = ks * 32 + (lane >> 4) * 8;
        const float* w = Wc + ((size_t)(m * 2 + h) * 64) * 64;
#pragma unroll
        for (int j = 0; j < 8; j++) val[j] = (short)f2b(w[(size_t)(kb + j) * 64 + o]);
        dst = wbc + ((size_t)m * 1024 + r) * 8;
    } else if (t < 10752) {               // dec
        int u = t - 9216;
        int m = u >> 9, r = u & 511;
        int nt = r >> 7, ks = (r >> 6) & 1, lane = r & 63;
        int h = nt >> 1, o = (nt & 1) * 16 + (lane & 15);
        int kb = ks * 32 + (lane >> 4) * 8;
        const float* w = Wd + ((size_t)(m * 2 + h) * 64) * 32;
#pragma unroll
        for (int j = 0; j < 8; j++) val[j] = (short)f2b(w[(size_t)(kb + j) * 32 + o]);
        dst = wbd + ((size_t)m * 512 + r) * 8;
    } else {                              // W_s
        int r = t - 10752;
        int nt = r >> 7, ks = (r >> 6) & 1, lane = r & 63;
        int n = nt * 16 + (lane & 15);
        int kb = ks * 32 + (lane >> 4) * 8;
#pragma unroll
        for (int j = 0; j < 8; j++) val[j] = (short)f2b(Ws[(size_t)(kb + j) * 128 + n]);
        dst = wbs + (size_t)r * 8;
    }
    *(bf16x8*)dst = val;
}

// ================= fused enc+conv (all metapaths in one launch) =================
#define HLS 133
__global__ __launch_bounds__(256) void k_encconv(const float* __restrict__ x,
                                                 const u16* __restrict__ wbe_all,
                                                 const float* __restrict__ be_all,
                                                 const u16* __restrict__ wbc_all,
                                                 u16* __restrict__ xw_all) {
    __shared__ float hl[64 * HLS];
    const int m = blockIdx.y;
    const int tid = threadIdx.x, lane = tid & 63, wave = tid >> 6;
    const int quad = lane >> 4, c16 = lane & 15;
    const int row = blockIdx.x * 64 + wave * 16 + c16;
    const bool ok = row < NN;
    const bf16x8* wbE = (const bf16x8*)(wbe_all + (size_t)m * 2048 * 8);
    const float* be = be_all + m * 2 * 64;
    u16* xw = xw_all + (size_t)m * NN * 128;
    f32x4 zero = {0.f, 0.f, 0.f, 0.f};
    f32x4 acc[8];
#pragma unroll
    for (int nt = 0; nt < 8; nt++) acc[nt] = zero;
#pragma unroll
    for (int ks = 0; ks < 4; ks++) {
        bf16x8 a = {0, 0, 0, 0, 0, 0, 0, 0};
        if (ok) {
            const float* xp = x + (size_t)row * 128 + ks * 32 + quad * 8;
            float4 xa = *(const float4*)xp;
            float4 xb = *(const float4*)(xp + 4);
            a[0] = (short)f2b(xa.x); a[1] = (short)f2b(xa.y);
            a[2] = (short)f2b(xa.z); a[3] = (short)f2b(xa.w);
            a[4] = (short)f2b(xb.x); a[5] = (short)f2b(xb.y);
            a[6] = (short)f2b(xb.z); a[7] = (short)f2b(xb.w);
        }
#pragma unroll
        for (int nt = 0; nt < 8; nt++)
            acc[nt] = __builtin_amdgcn_mfma_f32_16x16x32_bf16(a, wbE[(nt * 4 + ks) * 64 + lane], acc[nt], 0, 0, 0);
    }
    const int rbl = wave * 16 + quad * 4;
#pragma unroll
    for (int nt = 0; nt < 8; nt++) {
        int col = nt * 16 + c16, hh = col >> 6, o = col & 63;
        float bias = be[hh * 64 + o];
#pragma unroll
        for (int j = 0; j < 4; j++) {
            int rl = rbl + j;
            int rg = blockIdx.x * 64 + rl;
            hl[rl * HLS + col] = (rg < NN) ? lrelu(acc[nt][j] + bias) : 0.f;
        }
    }
    __syncthreads();
    const bf16x8* wbC = (const bf16x8*)(wbc_all + (size_t)m * 1024 * 8);
    f32x4 cacc[8];
#pragma unroll
    for (int nt = 0; nt < 8; nt++) cacc[nt] = zero;
    const int rl = wave * 16 + c16;
#pragma unroll
    for (int ks = 0; ks < 2; ks++) {
        bf16x8 a0, a1;
        const float* hp = &hl[rl * HLS + ks * 32 + quad * 8];
#pragma unroll
        for (int j = 0; j < 8; j++) { a0[j] = (short)f2b(hp[j]); a1[j] = (short)f2b(hp[64 + j]); }
#pragma unroll
        for (int nt = 0; nt < 8; nt++)
            cacc[nt] = __builtin_amdgcn_mfma_f32_16x16x32_bf16(nt < 4 ? a0 : a1, wbC[(nt * 2 + ks) * 64 + lane], cacc[nt], 0, 0, 0);
    }
#pragma unroll
    for (int nt = 0; nt < 8; nt++) {
        int col = nt * 16 + c16;
#pragma unroll
        for (int j = 0; j < 4; j++) {
            int r = blockIdx.x * 64 + rbl + j;
            if (r < NN) xw[(size_t)r * 128 + col] = f2b(cacc[nt][j]);
        }
    }
}

// ================= fused gather + post + score (all metapaths in one launch) =================
// Gather lands in LDS (ggl) and feeds post's MFMA directly: the gg global buffer,
// its HBM round-trip, and a whole latency-bound kernel disappear. One score atomic/block.
__global__ __launch_bounds__(512) void k_gpost(const int* __restrict__ sorted_all,
                                               const int* __restrict__ ofs_all,
                                               const float* __restrict__ rs_all,
                                               const u16* __restrict__ xw_all,
                                               const float* __restrict__ bconv_all,
                                               const u16* __restrict__ wbd_all,
                                               const float* __restrict__ bdec_all,
                                               const u16* __restrict__ wbs,
                                               const float* __restrict__ bs,
                                               const float* __restrict__ qv,
                                               u16* __restrict__ z_all,
                                               float* __restrict__ score) {
    __shared__ u16 ggl[64 * GLS];
    __shared__ float zl[64 * 68];
    __shared__ float spart[8];
    const int m = blockIdx.y;
    const int tid = threadIdx.x, lane = tid & 63, wave = tid >> 6;
    const int* sorted = sorted_all + (size_t)m * EE;
    const int* ofs = ofs_all + (size_t)m * (NN + 1);
    const float* rs = rs_all + (size_t)m * NN;
    const u16* xw = xw_all + (size_t)m * NN * 128;
    const float* bconv = bconv_all + m * 2 * 64;
    const float* bdec = bdec_all + m * 2 * 32;
    u16* z = z_all + (size_t)m * NN * 64;

    // ---- gather: 8 waves x 8 dsts, 4-edge ILP x 16-channel lanes ----
    const int p = lane >> 4, c = lane & 15;
    for (int d = 0; d < 8; d++) {
        int dl = wave * 8 + d;
        int dst = blockIdx.x * 64 + dl;
        if (dst < NN) {
            int beg = ofs[dst], end = ofs[dst + 1];
            float acc[8] = {0.f, 0.f, 0.f, 0.f, 0.f, 0.f, 0.f, 0.f};
            for (int j = beg + p; j < end; j += 4) {
                int s = sorted[j];
                float cf = rs[s];
                u16x8 v = *(const u16x8*)&xw[(size_t)s * 128 + c * 8];
#pragma unroll
                for (int k = 0; k < 8; k++) acc[k] = fmaf(cf, b2f(v[k]), acc[k]);
            }
#pragma unroll
            for (int k = 0; k < 8; k++) {
                acc[k] += __shfl_down(acc[k], 16);
                acc[k] += __shfl_down(acc[k], 32);
            }
            if (p == 0) {
                float rsd = rs[dst];
                u16x8 o;
#pragma unroll
                for (int k = 0; k < 8; k++) o[k] = f2b(acc[k] * rsd);
                *(u16x8*)&ggl[dl * GLS + c * 8] = o;
            }
        } else if (p == 0) {
            u16x8 o = {0, 0, 0, 0, 0, 0, 0, 0};
            *(u16x8*)&ggl[dl * GLS + c * 8] = o;
        }
    }
    __syncthreads();

    // ---- post MFMA (waves 0..3) ----
    f32x4 zero = {0.f, 0.f, 0.f, 0.f};
    const int quad = lane >> 4, c16 = lane & 15;
    if (wave < 4) {
        const int rl = wave * 16 + c16;
        const int row = blockIdx.x * 64 + rl;
        const bool ok = row < NN;
        float rs2 = 0.f;
        if (ok) { float t = rs[row]; rs2 = t * t; }
        const bf16x8* wd = (const bf16x8*)(wbd_all + (size_t)m * 512 * 8);
        f32x4 acc[4];
#pragma unroll
        for (int nt = 0; nt < 4; nt++) acc[nt] = zero;
#pragma unroll
        for (int ks = 0; ks < 2; ks++) {
            bf16x8 a0 = {0,0,0,0,0,0,0,0}, a1 = {0,0,0,0,0,0,0,0};
            if (ok) {
                int k0 = ks * 32 + quad * 8;
                const u16* gp0 = &ggl[rl * GLS + k0];
                const u16* gp1 = gp0 + 64;
                const u16* xp0 = &xw[(size_t)row * 128 + k0];
                const u16* xp1 = xp0 + 64;
#pragma unroll
                for (int j = 0; j < 8; j++) {
                    float v0 = lrelu(fmaf(b2f(xp0[j]), rs2, b2f(gp0[j])) + bconv[k0 + j]);
                    float v1 = lrelu(fmaf(b2f(xp1[j]), rs2, b2f(gp1[j])) + bconv[64 + k0 + j]);
                    a0[j] = (short)f2b(v0);
                    a1[j] = (short)f2b(v1);
                }
            }
#pragma unroll
            for (int nt = 0; nt < 4; nt++)
                acc[nt] = __builtin_amdgcn_mfma_f32_16x16x32_bf16(nt < 2 ? a0 : a1, wd[(nt * 2 + ks) * 64 + lane], acc[nt], 0, 0, 0);
        }
        const int rbl = wave * 16 + quad * 4;
#pragma unroll
        for (int nt = 0; nt < 4; nt++) {
            int col = nt * 16 + c16, hh = col >> 5, o = col & 31;
            float bias = bdec[hh * 32 + o];
#pragma unroll
            for (int j = 0; j < 4; j++) {
                int rl2 = rbl + j;
                int rg = blockIdx.x * 64 + rl2;
                zl[rl2 * 68 + col] = (rg < NN) ? (acc[nt][j] + bias) : 0.f;
            }
        }
    }
    __syncthreads();

    // ---- z store (bf16) + score MFMA (waves 0..3) ----
    float s = 0.f;
    if (wave < 4) {
        {
            int rl = tid >> 2, cq = tid & 3;
            int rg = blockIdx.x * 64 + rl;
            if (rg < NN) {
#pragma unroll
                for (int i = 0; i < 4; i++) {
                    int c4 = (cq * 4 + i) * 4;
                    float4 zv = *(const float4*)&zl[rl * 68 + c4];
                    ushort4 o;
                    o.x = f2b(zv.x); o.y = f2b(zv.y); o.z = f2b(zv.z); o.w = f2b(zv.w);
                    *(ushort4*)&z[(size_t)rg * 64 + c4] = o;
                }
            }
        }
        const bf16x8* wsb = (const bf16x8*)wbs;
        f32x4 sa[8];
#pragma unroll
        for (int nt = 0; nt < 8; nt++) sa[nt] = zero;
#pragma unroll
        for (int ks = 0; ks < 2; ks++) {
            bf16x8 a;
            const float* zp = &zl[(wave * 16 + c16) * 68 + ks * 32 + quad * 8];
#pragma unroll
            for (int j = 0; j < 8; j++) a[j] = (short)f2b(zp[j]);
#pragma unroll
            for (int nt = 0; nt < 8; nt++)
                sa[nt] = __builtin_amdgcn_mfma_f32_16x16x32_bf16(a, wsb[(nt * 2 + ks) * 64 + lane], sa[nt], 0, 0, 0);
        }
        const int rbl = wave * 16 + quad * 4;
#pragma unroll
        for (int nt = 0; nt < 8; nt++) {
            int col = nt * 16 + c16;
            float qc = qv[col], bb = bs[col];
#pragma unroll
            for (int j = 0; j < 4; j++) {
                int rg = blockIdx.x * 64 + rbl + j;
                if (rg < NN) s += fast_tanh(sa[nt][j] + bb) * qc;
            }
        }
#pragma unroll
        for (int off = 1; off < 64; off <<= 1) s += __shfl_xor(s, off);
    }
    if (lane == 0) spart[wave] = s;
    __syncthreads();
    if (tid == 0) {
        float t = spart[0] + spart[1] + spart[2] + spart[3];
        atomicAdd(&score[m], t);
    }
}

// ================= beta =================
__global__ void k_beta(const float* __restrict__ score, float* __restrict__ beta_ws,
                       float* __restrict__ out) {
    if (threadIdx.x == 0) {
        float s0 = score[0] / (float)NN, s1 = score[1] / (float)NN, s2 = score[2] / (float)NN;
        float mx = fmaxf(s0, fmaxf(s1, s2));
        float e0 = expf(s0 - mx), e1 = expf(s1 - mx), e2 = expf(s2 - mx);
        float inv = 1.f / (e0 + e1 + e2);
        beta_ws[0] = e0 * inv; beta_ws[1] = e1 * inv; beta_ws[2] = e2 * inv;
        out[800000] = e0 * inv; out[800001] = e1 * inv; out[800002] = e2 * inv;
    }
}

// ================= output: log_softmax((beta . z) @ W_o + b_o), z in bf16 =================
__global__ __launch_bounds__(256) void k_out(const u16* __restrict__ z,
                                             const float* __restrict__ beta,
                                             const float* __restrict__ Wo,
                                             const float* __restrict__ bo,
                                             float* __restrict__ out) {
    __shared__ float Zt[64 * 68];
    __shared__ float Wl[64 * 16];
    __shared__ float bl[16];
    const int tid = threadIdx.x, nbase = blockIdx.x * 64;
    float b0 = beta[0], b1 = beta[1], b2 = beta[2];
    for (int qq = tid; qq < 64 * 16; qq += 256) {
        int node = qq >> 4, k4 = qq & 15;
        int ng = nbase + node;
        float4 v = make_float4(0.f, 0.f, 0.f, 0.f);
        if (ng < NN) {
            ushort4 z0 = *(const ushort4*)&z[((size_t)0 * NN + ng) * 64 + k4 * 4];
            ushort4 z1 = *(const ushort4*)&z[((size_t)1 * NN + ng) * 64 + k4 * 4];
            ushort4 z2 = *(const ushort4*)&z[((size_t)2 * NN + ng) * 64 + k4 * 4];
            v.x = b0 * b2f(z0.x) + b1 * b2f(z1.x) + b2 * b2f(z2.x);
            v.y = b0 * b2f(z0.y) + b1 * b2f(z1.y) + b2 * b2f(z2.y);
            v.z = b0 * b2f(z0.z) + b1 * b2f(z1.z) + b2 * b2f(z2.z);
            v.w = b0 * b2f(z0.w) + b1 * b2f(z1.w) + b2 * b2f(z2.w);
        }
        *(float4*)&Zt[node * 68 + k4 * 4] = v;
    }
    for (int qq = tid; qq < 64 * 16 / 4; qq += 256)
        ((float4*)Wl)[qq] = ((const float4*)Wo)[qq];
    if (tid < 16) bl[tid] = bo[tid];
    __syncthreads();

    const int node = tid >> 2, cg = tid & 3;
    float4 a = make_float4(bl[cg * 4 + 0], bl[cg * 4 + 1], bl[cg * 4 + 2], bl[cg * 4 + 3]);
    for (int k = 0; k < 64; k++) {
        float zv = Zt[node * 68 + k];
        float4 w = *(const float4*)&Wl[k * 16 + cg * 4];
        a.x = fmaf(zv, w.x, a.x);
        a.y = fmaf(zv, w.y, a.y);
        a.z = fmaf(zv, w.z, a.z);
        a.w = fmaf(zv, w.w, a.w);
    }
    float mx = fmaxf(fmaxf(a.x, a.y), fmaxf(a.z, a.w));
    mx = fmaxf(mx, __shfl_xor(mx, 1));
    mx = fmaxf(mx, __shfl_xor(mx, 2));
    float sm = expf(a.x - mx) + expf(a.y - mx) + expf(a.z - mx) + expf(a.w - mx);
    sm += __shfl_xor(sm, 1);
    sm += __shfl_xor(sm, 2);
    float lse = mx + logf(sm);
    int ng = nbase + node;
    if (ng < NN) {
        float4 r = make_float4(a.x - lse, a.y - lse, a.z - lse, a.w - lse);
        *(float4*)&out[(size_t)ng * 16 + cg * 4] = r;
    }
}

extern "C" void kernel_launch(void* const* d_in, const int* in_sizes, int n_in,
                              void* d_out, int out_size, void* d_ws, size_t ws_size,
                              hipStream_t stream) {
    const float* x      = (const float*)d_in[0];
    const int*   ei     = (const int*)d_in[1];
    const float* W_enc  = (const float*)d_in[2];
    const float* b_enc  = (const float*)d_in[3];
    const float* W_conv = (const float*)d_in[4];
    const float* b_conv = (const float*)d_in[5];
    const float* W_dec  = (const float*)d_in[6];
    const float* b_dec  = (const float*)d_in[7];
    const float* W_s    = (const float*)d_in[8];
    const float* b_s    = (const float*)d_in[9];
    const float* qv     = (const float*)d_in[10];
    const float* W_o    = (const float*)d_in[11];
    const float* b_o    = (const float*)d_in[12];
    float* out = (float*)d_out;

    char* ws = (char*)d_ws;
    size_t off = 0;
    auto alloc = [&](size_t bytes) -> char* {
        char* p = ws + off;
        off = (off + bytes + 255) & ~(size_t)255;
        return p;
    };
    int*   row_ofs = (int*)alloc((size_t)MM * (NN + 1) * 4);
    float* rs      = (float*)alloc((size_t)MM * NN * 4);
    int*   sorted  = (int*)alloc((size_t)MM * EE * 4);
    u64*   queues  = (u64*)alloc((size_t)MM * NBKT * QCAP * 8);
    int*   gcur    = (int*)alloc((size_t)MM * NBKT * 4);
    int*   pbase   = (int*)alloc((size_t)MM * NBKT * 4);
    float* score   = (float*)alloc(64);
    float* beta_ws = (float*)alloc(64);
    u16*   wbe     = (u16*)alloc((size_t)MM * 2048 * 8 * 2);
    u16*   wbc     = (u16*)alloc((size_t)MM * 1024 * 8 * 2);
    u16*   wbd     = (u16*)alloc((size_t)MM * 512 * 8 * 2);
    u16*   wbs     = (u16*)alloc((size_t)1024 * 8 * 2);
    u16*   xw_buf  = (u16*)alloc((size_t)MM * NN * 128 * 2);   // all 3 metapaths
    u16*   z_buf   = (u16*)alloc((size_t)MM * NN * 64 * 2);    // bf16 z

    hipMemsetAsync(gcur, 0, (size_t)MM * NBKT * 4, stream);
    hipMemsetAsync(score, 0, 16, stream);

    dim3 gbkt(BBLK, MM);
    dim3 gcsr(NBKT, MM);
    k_bucket<<<gbkt, 256, 0, stream>>>(ei, queues, gcur);
    k_pscan<<<1, 64, 0, stream>>>(gcur, pbase);
    k_csr<<<gcsr, 512, 0, stream>>>(queues, gcur, pbase, row_ofs, rs, sorted);
    k_prep<<<46, 256, 0, stream>>>(W_enc, W_conv, W_dec, W_s, wbe, wbc, wbd, wbs);

    const int GB = (NN + 63) / 64;   // 782
    dim3 gmm(GB, MM);
    k_encconv<<<gmm, 256, 0, stream>>>(x, wbe, b_enc, wbc, xw_buf);
    k_gpost<<<gmm, 512, 0, stream>>>(sorted, row_ofs, rs, xw_buf,
                                     b_conv, wbd, b_dec, wbs, b_s, qv,
                                     z_buf, score);
    k_beta<<<1, 64, 0, stream>>>(score, beta_ws, out);
    k_out<<<GB, 256, 0, stream>>>(z_buf, beta_ws, W_o, b_o, out);
}

// Round 10
// 336.803 us; speedup vs baseline: 2.0322x; 1.1132x over previous
//
#include <hip/hip_runtime.h>

#define NN 50000
#define EE 800000
#define MM 3
#define HH 2
#define IND 128
#define HIDD 64
#define HEADD 32
#define OUTD 16
#define ATTD 128

#define NBKT 64            // fine dst-buckets per metapath
#define BSZ 782            // dsts per bucket (64*782 = 50048 >= NN)

#define NG4 200000         // EE/4 int4 groups per metapath
#define BBLK 196           // bucket blocks per metapath
#define QCAP 13200         // queue capacity per (m,bucket)

#define GLS 136            // ggl LDS row stride (u16)

typedef unsigned short u16;
typedef unsigned long long u64;
typedef short bf16x8 __attribute__((ext_vector_type(8)));
typedef unsigned short u16x8 __attribute__((ext_vector_type(8)));
typedef u64 u64x2 __attribute__((ext_vector_type(2)));
typedef float f32x4 __attribute__((ext_vector_type(4)));

__device__ __forceinline__ float lrelu(float v) { return v > 0.f ? v : 0.1f * v; }

__device__ __forceinline__ float fast_tanh(float x) {
    float ax = fabsf(x);
    float e = __expf(-2.0f * ax);
    float t = (1.0f - e) * __builtin_amdgcn_rcpf(1.0f + e);
    return copysignf(t, x);
}

__device__ __forceinline__ u16 f2b(float f) {          // fp32 -> bf16 RNE
    union { float f; unsigned int u; } v; v.f = f;
    unsigned int r = v.u + 0x7fffu + ((v.u >> 16) & 1u);
    return (u16)(r >> 16);
}
__device__ __forceinline__ float b2f(u16 u) {
    union { unsigned int u; float f; } v; v.u = ((unsigned int)u) << 16; return v.f;
}

// ================= phase A: bucket edges into 64 fine dst-buckets =================
__global__ __launch_bounds__(256) void k_bucket(const int* __restrict__ ei,
                                                u64* __restrict__ queues,
                                                int* __restrict__ gcur) {
    __shared__ int cnt[NBKT];
    __shared__ int base[NBKT];
    const int m = blockIdx.y, tid = threadIdx.x;
    const int4* s4 = (const int4*)(ei + (size_t)m * 2 * EE);
    const int4* d4 = (const int4*)(ei + (size_t)m * 2 * EE + EE);
    const int q0 = blockIdx.x * 1024;
    if (tid < NBKT) cnt[tid] = 0;
    __syncthreads();
#pragma unroll
    for (int i = 0; i < 4; i++) {
        int q = q0 + i * 256 + tid;
        if (q < NG4) {
            int4 dv = d4[q];
            atomicAdd(&cnt[dv.x / BSZ], 1);
            atomicAdd(&cnt[dv.y / BSZ], 1);
            atomicAdd(&cnt[dv.z / BSZ], 1);
            atomicAdd(&cnt[dv.w / BSZ], 1);
        }
    }
    __syncthreads();
    if (tid < NBKT) { base[tid] = atomicAdd(&gcur[m * NBKT + tid], cnt[tid]); cnt[tid] = 0; }
    __syncthreads();
#pragma unroll
    for (int i = 0; i < 4; i++) {
        int q = q0 + i * 256 + tid;
        if (q < NG4) {
            int4 dv = d4[q];
            int4 sv = s4[q];
            int ds[4] = {dv.x, dv.y, dv.z, dv.w};
            int ss[4] = {sv.x, sv.y, sv.z, sv.w};
#pragma unroll
            for (int e = 0; e < 4; e++) {
                int b = ds[e] / BSZ;
                int slot = base[b] + atomicAdd(&cnt[b], 1);
                if (slot < QCAP) {
                    u64 pk = ((u64)(unsigned)ds[e] << 32) | (unsigned)ss[e];
                    queues[((size_t)(m * NBKT + b)) * QCAP + slot] = pk;
                }
            }
        }
    }
}

// ================= bucket-base scan (3 x 64 values) =================
__global__ void k_pscan(const int* __restrict__ gcur, int* __restrict__ pbase) {
    int t = threadIdx.x;
    if (t < MM) {
        int run = 0;
        for (int b = 0; b < NBKT; b++) {
            int L = gcur[t * NBKT + b]; if (L > QCAP) L = QCAP;
            pbase[t * NBKT + b] = run; run += L;
        }
    }
}

// ================= CSR build: one block owns one (m, bucket) =================
__global__ __launch_bounds__(512) void k_csr(const u64* __restrict__ queues,
                                             const int* __restrict__ gcur,
                                             const int* __restrict__ pbase,
                                             int* __restrict__ ofs,
                                             float* __restrict__ rs,
                                             int* __restrict__ sorted) {
    __shared__ int cnt[BSZ];
    __shared__ int wscan[8];
    const int m = blockIdx.y;
    const int b = blockIdx.x;
    const int tid = threadIdx.x;
    const int lane = tid & 63, w = tid >> 6;
    int qlen = gcur[m * NBKT + b]; if (qlen > QCAP) qlen = QCAP;
    const u64* q = queues + ((size_t)(m * NBKT + b)) * QCAP;
    const u64x2* q2 = (const u64x2*)q;
    const int dlo = b * BSZ;
    const int nd = min(dlo + BSZ, NN) - dlo;
    const int n2 = qlen >> 1;
    for (int i = tid; i < BSZ; i += 512) cnt[i] = 0;
    __syncthreads();
    for (int i = tid; i < n2; i += 512) {
        u64x2 e = q2[i];
        atomicAdd(&cnt[(int)(e.x >> 32) - dlo], 1);
        atomicAdd(&cnt[(int)(e.y >> 32) - dlo], 1);
    }
    if (tid == 0 && (qlen & 1))
        atomicAdd(&cnt[(int)(q[qlen - 1] >> 32) - dlo], 1);
    __syncthreads();
    const int c0 = tid * 2;
    int v0 = (c0 < BSZ) ? cnt[c0] : 0;
    int v1 = (c0 + 1 < BSZ) ? cnt[c0 + 1] : 0;
    int s = v0 + v1;
    int vv = s;
    for (int off = 1; off < 64; off <<= 1) { int t = __shfl_up(vv, off); if (lane >= off) vv += t; }
    if (lane == 63) wscan[w] = vv;
    __syncthreads();
    if (tid == 0) { int run = 0; for (int j = 0; j < 8; j++) { int t = wscan[j]; wscan[j] = run; run += t; } }
    __syncthreads();
    int excl = wscan[w] + vv - s;
    int g0 = pbase[m * NBKT + b] + excl;
    int g1 = g0 + v0;
    if (c0 < nd) {
        ofs[(size_t)m * (NN + 1) + dlo + c0] = g0;
        rs[(size_t)m * NN + dlo + c0] = rsqrtf((float)(v0 + 1));
    }
    if (c0 + 1 < nd) {
        ofs[(size_t)m * (NN + 1) + dlo + c0 + 1] = g1;
        rs[(size_t)m * NN + dlo + c0 + 1] = rsqrtf((float)(v1 + 1));
    }
    if (b == NBKT - 1 && tid == 0)
        ofs[(size_t)m * (NN + 1) + NN] = EE;
    __syncthreads();
    if (c0 < BSZ) cnt[c0] = g0;
    if (c0 + 1 < BSZ) cnt[c0 + 1] = g1;
    __syncthreads();
    int* srt = sorted + (size_t)m * EE;
    for (int i = tid; i < n2; i += 512) {
        u64x2 e = q2[i];
        int p0 = atomicAdd(&cnt[(int)(e.x >> 32) - dlo], 1);
        srt[p0] = (int)(e.x & 0xffffffffu);
        int p1 = atomicAdd(&cnt[(int)(e.y >> 32) - dlo], 1);
        srt[p1] = (int)(e.y & 0xffffffffu);
    }
    if (tid == 0 && (qlen & 1)) {
        u64 e = q[qlen - 1];
        int p0 = atomicAdd(&cnt[(int)(e >> 32) - dlo], 1);
        srt[p0] = (int)(e & 0xffffffffu);
    }
}

// ================= weight prep: fp32 -> bf16 MFMA B-fragment layout =================
__global__ __launch_bounds__(256) void k_prep(const float* __restrict__ We, const float* __restrict__ Wc,
                                              const float* __restrict__ Wd, const float* __restrict__ Ws,
                                              u16* __restrict__ wbe, u16* __restrict__ wbc,
                                              u16* __restrict__ wbd, u16* __restrict__ wbs) {
    int t = blockIdx.x * 256 + threadIdx.x;
    if (t >= 11776) return;
    bf16x8 val;
    u16* dst;
    if (t < 6144) {                       // enc
        int m = t >> 11, r = t & 2047;
        int nt = r >> 8, ks = (r >> 6) & 3, lane = r & 63;
        int n = nt * 16 + (lane & 15), h = n >> 6, o = n & 63;
        int kb = ks * 32 + (lane >> 4) * 8;
        const float* w = We + ((size_t)(m * 2 + h) * 128) * 64;
#pragma unroll
        for (int j = 0; j < 8; j++) val[j] = (short)f2b(w[(size_t)(kb + j) * 64 + o]);
        dst = wbe + ((size_t)m * 2048 + r) * 8;
    } else if (t < 9216) {                // conv
        int u = t - 6144;
        int m = u >> 10, r = u & 1023;
        int nt = r >> 7, ks = (r >> 6) & 1, lane = r & 63;
        int h = nt >> 2, o = (nt & 3) * 16 + (lane & 15);
        int kb = ks * 32 + (lane >> 4) * 8;
        const float* w = Wc + ((size_t)(m * 2 + h) * 64) * 64;
#pragma unroll
        for (int j = 0; j < 8; j++) val[j] = (short)f2b(w[(size_t)(kb + j) * 64 + o]);
        dst = wbc + ((size_t)m * 1024 + r) * 8;
    } else if (t < 10752) {               // dec
        int u = t - 9216;
        int m = u >> 9, r = u & 511;
        int nt = r >> 7, ks = (r >> 6) & 1, lane = r & 63;
        int h = nt >> 1, o = (nt & 1) * 16 + (lane & 15);
        int kb = ks * 32 + (lane >> 4) * 8;
        const float* w = Wd + ((size_t)(m * 2 + h) * 64) * 32;
#pragma unroll
        for (int j = 0; j < 8; j++) val[j] = (short)f2b(w[(size_t)(kb + j) * 32 + o]);
        dst = wbd + ((size_t)m * 512 + r) * 8;
    } else {                              // W_s
        int r = t - 10752;
        int nt = r >> 7, ks = (r >> 6) & 1, lane = r & 63;
        int n = nt * 16 + (lane & 15);
        int kb = ks * 32 + (lane >> 4) * 8;
#pragma unroll
        for (int j = 0; j < 8; j++) val[j] = (short)f2b(Ws[(size_t)(kb + j) * 128 + n]);
        dst = wbs + (size_t)r * 8;
    }
    *(bf16x8*)dst = val;
}

// ================= fused enc+conv: writes xw' = rs[row] * (h @ W_conv)  =================
// Pre-scaling by rs[src] removes the per-edge random rs load from the gather's
// dependency chain (agg*rs_d = rs_d * (sum xw'_src + xw'_dst)).
#define HLS 133
__global__ __launch_bounds__(256) void k_encconv(const float* __restrict__ x,
                                                 const u16* __restrict__ wbe_all,
                                                 const float* __restrict__ be_all,
                                                 const u16* __restrict__ wbc_all,
                                                 const float* __restrict__ rs_all,
                                                 u16* __restrict__ xw_all) {
    __shared__ float hl[64 * HLS];
    const int m = blockIdx.y;
    const int tid = threadIdx.x, lane = tid & 63, wave = tid >> 6;
    const int quad = lane >> 4, c16 = lane & 15;
    const int row = blockIdx.x * 64 + wave * 16 + c16;
    const bool ok = row < NN;
    const bf16x8* wbE = (const bf16x8*)(wbe_all + (size_t)m * 2048 * 8);
    const float* be = be_all + m * 2 * 64;
    const float* rs = rs_all + (size_t)m * NN;
    u16* xw = xw_all + (size_t)m * NN * 128;
    f32x4 zero = {0.f, 0.f, 0.f, 0.f};
    f32x4 acc[8];
#pragma unroll
    for (int nt = 0; nt < 8; nt++) acc[nt] = zero;
#pragma unroll
    for (int ks = 0; ks < 4; ks++) {
        bf16x8 a = {0, 0, 0, 0, 0, 0, 0, 0};
        if (ok) {
            const float* xp = x + (size_t)row * 128 + ks * 32 + quad * 8;
            float4 xa = *(const float4*)xp;
            float4 xb = *(const float4*)(xp + 4);
            a[0] = (short)f2b(xa.x); a[1] = (short)f2b(xa.y);
            a[2] = (short)f2b(xa.z); a[3] = (short)f2b(xa.w);
            a[4] = (short)f2b(xb.x); a[5] = (short)f2b(xb.y);
            a[6] = (short)f2b(xb.z); a[7] = (short)f2b(xb.w);
        }
#pragma unroll
        for (int nt = 0; nt < 8; nt++)
            acc[nt] = __builtin_amdgcn_mfma_f32_16x16x32_bf16(a, wbE[(nt * 4 + ks) * 64 + lane], acc[nt], 0, 0, 0);
    }
    const int rbl = wave * 16 + quad * 4;
#pragma unroll
    for (int nt = 0; nt < 8; nt++) {
        int col = nt * 16 + c16, hh = col >> 6, o = col & 63;
        float bias = be[hh * 64 + o];
#pragma unroll
        for (int j = 0; j < 4; j++) {
            int rl = rbl + j;
            int rg = blockIdx.x * 64 + rl;
            hl[rl * HLS + col] = (rg < NN) ? lrelu(acc[nt][j] + bias) : 0.f;
        }
    }
    __syncthreads();
    const bf16x8* wbC = (const bf16x8*)(wbc_all + (size_t)m * 1024 * 8);
    f32x4 cacc[8];
#pragma unroll
    for (int nt = 0; nt < 8; nt++) cacc[nt] = zero;
    const int rl = wave * 16 + c16;
#pragma unroll
    for (int ks = 0; ks < 2; ks++) {
        bf16x8 a0, a1;
        const float* hp = &hl[rl * HLS + ks * 32 + quad * 8];
#pragma unroll
        for (int j = 0; j < 8; j++) { a0[j] = (short)f2b(hp[j]); a1[j] = (short)f2b(hp[64 + j]); }
#pragma unroll
        for (int nt = 0; nt < 8; nt++)
            cacc[nt] = __builtin_amdgcn_mfma_f32_16x16x32_bf16(nt < 4 ? a0 : a1, wbC[(nt * 2 + ks) * 64 + lane], cacc[nt], 0, 0, 0);
    }
    float rsv[4];
#pragma unroll
    for (int j = 0; j < 4; j++) {
        int r = blockIdx.x * 64 + rbl + j;
        rsv[j] = (r < NN) ? rs[r] : 0.f;
    }
#pragma unroll
    for (int nt = 0; nt < 8; nt++) {
        int col = nt * 16 + c16;
#pragma unroll
        for (int j = 0; j < 4; j++) {
            int r = blockIdx.x * 64 + rbl + j;
            if (r < NN) xw[(size_t)r * 128 + col] = f2b(cacc[nt][j] * rsv[j]);
        }
    }
}

// ================= fused gather + post + score =================
// gather: acc = sum xw'_src + xw'_dst; ggl = rs[dst] * acc  (pre-scaled xw').
// 2-deep unrolled row loads + index prefetch -> 8 rows in flight per wave.
__global__ __launch_bounds__(512) void k_gpost(const int* __restrict__ sorted_all,
                                               const int* __restrict__ ofs_all,
                                               const float* __restrict__ rs_all,
                                               const u16* __restrict__ xw_all,
                                               const float* __restrict__ bconv_all,
                                               const u16* __restrict__ wbd_all,
                                               const float* __restrict__ bdec_all,
                                               const u16* __restrict__ wbs,
                                               const float* __restrict__ bs,
                                               const float* __restrict__ qv,
                                               u16* __restrict__ z_all,
                                               float* __restrict__ score) {
    __shared__ u16 ggl[64 * GLS];
    __shared__ float zl[64 * 68];
    __shared__ float spart[8];
    const int m = blockIdx.y;
    const int tid = threadIdx.x, lane = tid & 63, wave = tid >> 6;
    const int* sorted = sorted_all + (size_t)m * EE;
    const int* ofs = ofs_all + (size_t)m * (NN + 1);
    const float* rs = rs_all + (size_t)m * NN;
    const u16* xw = xw_all + (size_t)m * NN * 128;
    const float* bconv = bconv_all + m * 2 * 64;
    const float* bdec = bdec_all + m * 2 * 32;
    u16* z = z_all + (size_t)m * NN * 64;

    // ---- gather: 8 waves x 8 dsts, 4 edge-groups x 16 ch-lanes, 2-deep unroll ----
    const int p = lane >> 4, c = lane & 15;
    for (int d = 0; d < 8; d++) {
        int dl = wave * 8 + d;
        int dst = blockIdx.x * 64 + dl;
        if (dst < NN) {
            int beg = ofs[dst], end = ofs[dst + 1];
            float acc[8] = {0.f, 0.f, 0.f, 0.f, 0.f, 0.f, 0.f, 0.f};
            int j0 = beg + p;
            while (j0 < end) {
                int s0 = sorted[j0];
                int j1 = j0 + 4;
                bool h1 = j1 < end;
                int s1 = h1 ? sorted[j1] : s0;
                u16x8 v0 = *(const u16x8*)&xw[(size_t)s0 * 128 + c * 8];
                u16x8 v1 = *(const u16x8*)&xw[(size_t)s1 * 128 + c * 8];
#pragma unroll
                for (int k = 0; k < 8; k++) acc[k] += b2f(v0[k]);
                if (h1) {
#pragma unroll
                    for (int k = 0; k < 8; k++) acc[k] += b2f(v1[k]);
                }
                j0 += 8;
            }
#pragma unroll
            for (int k = 0; k < 8; k++) {
                acc[k] += __shfl_down(acc[k], 16);
                acc[k] += __shfl_down(acc[k], 32);
            }
            if (p == 0) {
                u16x8 own = *(const u16x8*)&xw[(size_t)dst * 128 + c * 8];
                float rsd = rs[dst];
                u16x8 o;
#pragma unroll
                for (int k = 0; k < 8; k++) o[k] = f2b((acc[k] + b2f(own[k])) * rsd);
                *(u16x8*)&ggl[dl * GLS + c * 8] = o;
            }
        } else if (p == 0) {
            u16x8 o = {0, 0, 0, 0, 0, 0, 0, 0};
            *(u16x8*)&ggl[dl * GLS + c * 8] = o;
        }
    }
    __syncthreads();

    // ---- post MFMA (waves 0..3): a = lrelu(ggl + bconv) @ W_dec ----
    f32x4 zero = {0.f, 0.f, 0.f, 0.f};
    const int quad = lane >> 4, c16 = lane & 15;
    if (wave < 4) {
        const int rl = wave * 16 + c16;
        const bf16x8* wd = (const bf16x8*)(wbd_all + (size_t)m * 512 * 8);
        f32x4 acc[4];
#pragma unroll
        for (int nt = 0; nt < 4; nt++) acc[nt] = zero;
#pragma unroll
        for (int ks = 0; ks < 2; ks++) {
            bf16x8 a0, a1;
            int k0 = ks * 32 + quad * 8;
            const u16* gp0 = &ggl[rl * GLS + k0];
            const u16* gp1 = gp0 + 64;
#pragma unroll
            for (int j = 0; j < 8; j++) {
                a0[j] = (short)f2b(lrelu(b2f(gp0[j]) + bconv[k0 + j]));
                a1[j] = (short)f2b(lrelu(b2f(gp1[j]) + bconv[64 + k0 + j]));
            }
#pragma unroll
            for (int nt = 0; nt < 4; nt++)
                acc[nt] = __builtin_amdgcn_mfma_f32_16x16x32_bf16(nt < 2 ? a0 : a1, wd[(nt * 2 + ks) * 64 + lane], acc[nt], 0, 0, 0);
        }
        const int rbl = wave * 16 + quad * 4;
#pragma unroll
        for (int nt = 0; nt < 4; nt++) {
            int col = nt * 16 + c16, hh = col >> 5, o = col & 31;
            float bias = bdec[hh * 32 + o];
#pragma unroll
            for (int j = 0; j < 4; j++) {
                int rl2 = rbl + j;
                int rg = blockIdx.x * 64 + rl2;
                zl[rl2 * 68 + col] = (rg < NN) ? (acc[nt][j] + bias) : 0.f;
            }
        }
    }
    __syncthreads();

    // ---- z store (bf16) + score MFMA (waves 0..3) ----
    float s = 0.f;
    if (wave < 4) {
        {
            int rl = tid >> 2, cq = tid & 3;
            int rg = blockIdx.x * 64 + rl;
            if (rg < NN) {
#pragma unroll
                for (int i = 0; i < 4; i++) {
                    int c4 = (cq * 4 + i) * 4;
                    float4 zv = *(const float4*)&zl[rl * 68 + c4];
                    ushort4 o;
                    o.x = f2b(zv.x); o.y = f2b(zv.y); o.z = f2b(zv.z); o.w = f2b(zv.w);
                    *(ushort4*)&z[(size_t)rg * 64 + c4] = o;
                }
            }
        }
        const bf16x8* wsb = (const bf16x8*)wbs;
        f32x4 sa[8];
#pragma unroll
        for (int nt = 0; nt < 8; nt++) sa[nt] = zero;
#pragma unroll
        for (int ks = 0; ks < 2; ks++) {
            bf16x8 a;
            const float* zp = &zl[(wave * 16 + c16) * 68 + ks * 32 + quad * 8];
#pragma unroll
            for (int j = 0; j < 8; j++) a[j] = (short)f2b(zp[j]);
#pragma unroll
            for (int nt = 0; nt < 8; nt++)
                sa[nt] = __builtin_amdgcn_mfma_f32_16x16x32_bf16(a, wsb[(nt * 2 + ks) * 64 + lane], sa[nt], 0, 0, 0);
        }
        const int rbl = wave * 16 + quad * 4;
#pragma unroll
        for (int nt = 0; nt < 8; nt++) {
            int col = nt * 16 + c16;
            float qc = qv[col], bb = bs[col];
#pragma unroll
            for (int j = 0; j < 4; j++) {
                int rg = blockIdx.x * 64 + rbl + j;
                if (rg < NN) s += fast_tanh(sa[nt][j] + bb) * qc;
            }
        }
#pragma unroll
        for (int off = 1; off < 64; off <<= 1) s += __shfl_xor(s, off);
    }
    if (lane == 0) spart[wave] = s;
    __syncthreads();
    if (tid == 0) {
        float t = spart[0] + spart[1] + spart[2] + spart[3];
        atomicAdd(&score[m], t);
    }
}

// ================= beta =================
__global__ void k_beta(const float* __restrict__ score, float* __restrict__ beta_ws,
                       float* __restrict__ out) {
    if (threadIdx.x == 0) {
        float s0 = score[0] / (float)NN, s1 = score[1] / (float)NN, s2 = score[2] / (float)NN;
        float mx = fmaxf(s0, fmaxf(s1, s2));
        float e0 = expf(s0 - mx), e1 = expf(s1 - mx), e2 = expf(s2 - mx);
        float inv = 1.f / (e0 + e1 + e2);
        beta_ws[0] = e0 * inv; beta_ws[1] = e1 * inv; beta_ws[2] = e2 * inv;
        out[800000] = e0 * inv; out[800001] = e1 * inv; out[800002] = e2 * inv;
    }
}

// ================= output: log_softmax((beta . z) @ W_o + b_o), z in bf16 =================
__global__ __launch_bounds__(256) void k_out(const u16* __restrict__ z,
                                             const float* __restrict__ beta,
                                             const float* __restrict__ Wo,
                                             const float* __restrict__ bo,
                                             float* __restrict__ out) {
    __shared__ float Zt[64 * 68];
    __shared__ float Wl[64 * 16];
    __shared__ float bl[16];
    const int tid = threadIdx.x, nbase = blockIdx.x * 64;
    float b0 = beta[0], b1 = beta[1], b2 = beta[2];
    for (int qq = tid; qq < 64 * 16; qq += 256) {
        int node = qq >> 4, k4 = qq & 15;
        int ng = nbase + node;
        float4 v = make_float4(0.f, 0.f, 0.f, 0.f);
        if (ng < NN) {
            ushort4 z0 = *(const ushort4*)&z[((size_t)0 * NN + ng) * 64 + k4 * 4];
            ushort4 z1 = *(const ushort4*)&z[((size_t)1 * NN + ng) * 64 + k4 * 4];
            ushort4 z2 = *(const ushort4*)&z[((size_t)2 * NN + ng) * 64 + k4 * 4];
            v.x = b0 * b2f(z0.x) + b1 * b2f(z1.x) + b2 * b2f(z2.x);
            v.y = b0 * b2f(z0.y) + b1 * b2f(z1.y) + b2 * b2f(z2.y);
            v.z = b0 * b2f(z0.z) + b1 * b2f(z1.z) + b2 * b2f(z2.z);
            v.w = b0 * b2f(z0.w) + b1 * b2f(z1.w) + b2 * b2f(z2.w);
        }
        *(float4*)&Zt[node * 68 + k4 * 4] = v;
    }
    for (int qq = tid; qq < 64 * 16 / 4; qq += 256)
        ((float4*)Wl)[qq] = ((const float4*)Wo)[qq];
    if (tid < 16) bl[tid] = bo[tid];
    __syncthreads();

    const int node = tid >> 2, cg = tid & 3;
    float4 a = make_float4(bl[cg * 4 + 0], bl[cg * 4 + 1], bl[cg * 4 + 2], bl[cg * 4 + 3]);
    for (int k = 0; k < 64; k++) {
        float zv = Zt[node * 68 + k];
        float4 w = *(const float4*)&Wl[k * 16 + cg * 4];
        a.x = fmaf(zv, w.x, a.x);
        a.y = fmaf(zv, w.y, a.y);
        a.z = fmaf(zv, w.z, a.z);
        a.w = fmaf(zv, w.w, a.w);
    }
    float mx = fmaxf(fmaxf(a.x, a.y), fmaxf(a.z, a.w));
    mx = fmaxf(mx, __shfl_xor(mx, 1));
    mx = fmaxf(mx, __shfl_xor(mx, 2));
    float sm = expf(a.x - mx) + expf(a.y - mx) + expf(a.z - mx) + expf(a.w - mx);
    sm += __shfl_xor(sm, 1);
    sm += __shfl_xor(sm, 2);
    float lse = mx + logf(sm);
    int ng = nbase + node;
    if (ng < NN) {
        float4 r = make_float4(a.x - lse, a.y - lse, a.z - lse, a.w - lse);
        *(float4*)&out[(size_t)ng * 16 + cg * 4] = r;
    }
}

extern "C" void kernel_launch(void* const* d_in, const int* in_sizes, int n_in,
                              void* d_out, int out_size, void* d_ws, size_t ws_size,
                              hipStream_t stream) {
    const float* x      = (const float*)d_in[0];
    const int*   ei     = (const int*)d_in[1];
    const float* W_enc  = (const float*)d_in[2];
    const float* b_enc  = (const float*)d_in[3];
    const float* W_conv = (const float*)d_in[4];
    const float* b_conv = (const float*)d_in[5];
    const float* W_dec  = (const float*)d_in[6];
    const float* b_dec  = (const float*)d_in[7];
    const float* W_s    = (const float*)d_in[8];
    const float* b_s    = (const float*)d_in[9];
    const float* qv     = (const float*)d_in[10];
    const float* W_o    = (const float*)d_in[11];
    const float* b_o    = (const float*)d_in[12];
    float* out = (float*)d_out;

    char* ws = (char*)d_ws;
    size_t off = 0;
    auto alloc = [&](size_t bytes) -> char* {
        char* p = ws + off;
        off = (off + bytes + 255) & ~(size_t)255;
        return p;
    };
    int*   row_ofs = (int*)alloc((size_t)MM * (NN + 1) * 4);
    float* rs      = (float*)alloc((size_t)MM * NN * 4);
    int*   sorted  = (int*)alloc((size_t)MM * EE * 4);
    u64*   queues  = (u64*)alloc((size_t)MM * NBKT * QCAP * 8);
    int*   gcur    = (int*)alloc((size_t)MM * NBKT * 4);
    int*   pbase   = (int*)alloc((size_t)MM * NBKT * 4);
    float* score   = (float*)alloc(64);
    float* beta_ws = (float*)alloc(64);
    u16*   wbe     = (u16*)alloc((size_t)MM * 2048 * 8 * 2);
    u16*   wbc     = (u16*)alloc((size_t)MM * 1024 * 8 * 2);
    u16*   wbd     = (u16*)alloc((size_t)MM * 512 * 8 * 2);
    u16*   wbs     = (u16*)alloc((size_t)1024 * 8 * 2);
    u16*   xw_buf  = (u16*)alloc((size_t)MM * NN * 128 * 2);
    u16*   z_buf   = (u16*)alloc((size_t)MM * NN * 64 * 2);

    hipMemsetAsync(gcur, 0, (size_t)MM * NBKT * 4, stream);
    hipMemsetAsync(score, 0, 16, stream);

    dim3 gbkt(BBLK, MM);
    dim3 gcsr(NBKT, MM);
    k_bucket<<<gbkt, 256, 0, stream>>>(ei, queues, gcur);
    k_pscan<<<1, 64, 0, stream>>>(gcur, pbase);
    k_csr<<<gcsr, 512, 0, stream>>>(queues, gcur, pbase, row_ofs, rs, sorted);
    k_prep<<<46, 256, 0, stream>>>(W_enc, W_conv, W_dec, W_s, wbe, wbc, wbd, wbs);

    const int GB = (NN + 63) / 64;   // 782
    dim3 gmm(GB, MM);
    k_encconv<<<gmm, 256, 0, stream>>>(x, wbe, b_enc, wbc, rs, xw_buf);
    k_gpost<<<gmm, 512, 0, stream>>>(sorted, row_ofs, rs, xw_buf,
                                     b_conv, wbd, b_dec, wbs, b_s, qv,
                                     z_buf, score);
    k_beta<<<1, 64, 0, stream>>>(score, beta_ws, out);
    k_out<<<GB, 256, 0, stream>>>(z_buf, beta_ws, W_o, b_o, out);
}